// Round 5
// baseline (370.213 us; speedup 1.0000x reference)
//
#include <hip/hip_runtime.h>
#include <hip/hip_bf16.h>

#define T_SEQ 2048
#define DM    2048
#define NH    16
#define DH    128
#define NBH   32          // B * NH
#define MROWS 4096        // B * T

typedef __bf16 bf16x8 __attribute__((ext_vector_type(8)));
typedef __bf16 bf16x4 __attribute__((ext_vector_type(4)));
typedef float  f32x4  __attribute__((ext_vector_type(4)));

#define MFMA16 __builtin_amdgcn_mfma_f32_16x16x32_bf16

__device__ __forceinline__ void async_copy16(const void* g, void* l) {
  __builtin_amdgcn_global_load_lds((const __attribute__((address_space(1))) void*)g,
                                   (__attribute__((address_space(3))) void*)l, 16, 0, 0);
}

// ---------------- prep kernels ----------------

__global__ void cast_bf16_k(const float* __restrict__ x, __bf16* __restrict__ xb) {
  int i = (blockIdx.x * 256 + threadIdx.x) * 4;
  float4 v = *reinterpret_cast<const float4*>(x + i);
  bf16x4 o;
  o[0] = (__bf16)v.x; o[1] = (__bf16)v.y; o[2] = (__bf16)v.z; o[3] = (__bf16)v.w;
  *reinterpret_cast<bf16x4*>(xb + i) = o;
}

// W [K][N] f32 -> WT [N][K] bf16
__global__ void transpose_cast_w(const float* __restrict__ W, __bf16* __restrict__ WT,
                                 int K, int N) {
  __shared__ float tile[32][33];
  int n0 = blockIdx.x * 32, k0 = blockIdx.y * 32;
  int tx = threadIdx.x, ty = threadIdx.y;
  #pragma unroll
  for (int i = 0; i < 4; i++)
    tile[ty + i * 8][tx] = W[(size_t)(k0 + ty + i * 8) * N + n0 + tx];
  __syncthreads();
  #pragma unroll
  for (int i = 0; i < 4; i++)
    WT[(size_t)(n0 + ty + i * 8) * K + k0 + tx] = (__bf16)tile[tx][ty + i * 8];
}

// Vb [BH][T][D] bf16 -> Vtb [BH][D][T] bf16
__global__ void transpose_v(const __bf16* __restrict__ Vb, __bf16* __restrict__ Vtb) {
  __shared__ __bf16 tile[32][34];
  int t0 = blockIdx.x * 32, d0 = blockIdx.y * 32, bh = blockIdx.z;
  const __bf16* src = Vb + (size_t)bh * T_SEQ * DH;
  __bf16* dst = Vtb + (size_t)bh * DH * T_SEQ;
  int tx = threadIdx.x, ty = threadIdx.y;
  #pragma unroll
  for (int i = 0; i < 4; i++)
    tile[ty + i * 8][tx] = src[(size_t)(t0 + ty + i * 8) * DH + d0 + tx];
  __syncthreads();
  #pragma unroll
  for (int i = 0; i < 4; i++)
    dst[(size_t)(d0 + ty + i * 8) * T_SEQ + t0 + tx] = tile[tx][ty + i * 8];
}

// ------- GEMM (C = A * Bt^T), BM=BN=128, BK=32, 4 waves, 1 barrier/K-tile -------
// LDS tile [128 rows][32 bf16] = 64-B rows, chunk-XOR swizzled: 16-B slot s of
// row r holds global chunk s ^ (r&3). Staged via global_load_lds (linear dest,
// inverse-swizzled global source); reads apply the same XOR (residual 4-way
// conflict ~1.58x on ds_read — traded for 32 KB LDS -> 4 blocks/CU TLP).

__device__ __forceinline__ bf16x8 rds32(const __bf16* base, int row, int chunk) {
  return *reinterpret_cast<const bf16x8*>(
      reinterpret_cast<const char*>(base) + row * 64 + ((chunk ^ (row & 3)) << 4));
}

// stage one 128x32 tile (8 KB): 2 global_load_lds per wave
__device__ __forceinline__ void stage32(const __bf16* g, int K, int kt, char* lds,
                                        int wave, int lane) {
  #pragma unroll
  for (int j = 0; j < 2; j++) {
    int r = wave * 32 + j * 16 + (lane >> 2);
    int c = lane & 3;
    const char* src = (const char*)g + (size_t)r * (K * 2) + kt * 64 + ((c ^ (r & 3)) << 4);
    async_copy16(src, lds + wave * 2048 + j * 1024);
  }
}

template <int EPI>
__global__ __launch_bounds__(256, 4) void gemm_bt(
    const __bf16* __restrict__ A, const __bf16* __restrict__ Bt, int K,
    const float* __restrict__ bias,
    const float* __restrict__ fcos, const float* __restrict__ fsin,
    __bf16* __restrict__ Qb, __bf16* __restrict__ Kb, __bf16* __restrict__ Vb,
    float* __restrict__ kout, float* __restrict__ vout,
    float* __restrict__ outp) {
  __shared__ __bf16 As[2][128 * 32];   // 2 x 8 KB
  __shared__ __bf16 Bs[2][128 * 32];   // 2 x 8 KB  (32 KB total -> 4 blocks/CU)
  const int tid = threadIdx.x, lane = tid & 63, wave = tid >> 6;
  const int hi = lane >> 4, lo = lane & 15;
  const int wm = (wave >> 1) * 64, wn = (wave & 1) * 64;
  const __bf16* Ab = A + (size_t)blockIdx.y * 128 * K;
  const __bf16* Bb = Bt + (size_t)blockIdx.x * 128 * K;
  f32x4 acc[4][4] = {};
  const int NK = K >> 5;

  stage32(Ab, K, 0, (char*)As[0], wave, lane);
  stage32(Bb, K, 0, (char*)Bs[0], wave, lane);
  __syncthreads();   // drains vmcnt: tile 0 ready

  for (int t = 0; t < NK; ++t) {
    const int cur = t & 1;
    if (t + 1 < NK) {
      stage32(Ab, K, t + 1, (char*)As[cur ^ 1], wave, lane);
      stage32(Bb, K, t + 1, (char*)Bs[cur ^ 1], wave, lane);
    }
    bf16x8 a[4], b[4];
    #pragma unroll
    for (int m = 0; m < 4; ++m) a[m] = rds32(As[cur], wm + m * 16 + lo, hi);
    #pragma unroll
    for (int n = 0; n < 4; ++n) b[n] = rds32(Bs[cur], wn + n * 16 + lo, hi);
    #pragma unroll
    for (int m = 0; m < 4; ++m)
      #pragma unroll
      for (int n = 0; n < 4; ++n)
        acc[m][n] = MFMA16(a[m], b[n], acc[m][n], 0, 0, 0);
    // single barrier per K-tile: all reads of cur done; next-tile staging
    // (issued at top) drains via the implicit vmcnt(0) here.
    __syncthreads();
  }

  // epilogue. C frag layout: row = hi*4 + r, col = lo (verified m89/m91)
  #pragma unroll
  for (int j = 0; j < 4; j++) {
    int n = blockIdx.x * 128 + wn + j * 16 + lo;
    float bv = bias[n];
    if (EPI == 1) {
      int which = n >> 11, wn2 = n & 2047, h = wn2 >> 7, d = wn2 & 127, jj = d >> 1;
      #pragma unroll
      for (int i = 0; i < 4; i++) {
        #pragma unroll
        for (int r = 0; r < 4; r++) {
          int row = blockIdx.y * 128 + wm + i * 16 + hi * 4 + r;
          int b = row >> 11, tt = row & 2047;
          float v = acc[i][j][r] + bv;
          float other = __shfl_xor(v, 1, 64);   // rope pair partner (cols n, n^1)
          float res = v;
          if (which < 2) {
            float c = fcos[tt * 64 + jj], s = fsin[tt * 64 + jj];
            res = (d & 1) ? (other * s + v * c) : (v * c - other * s);
          }
          size_t idx = (((size_t)(b * NH + h)) * T_SEQ + tt) * DH + d;
          if (which == 0) {
            Qb[idx] = (__bf16)res;
          } else if (which == 1) {
            Kb[idx] = (__bf16)res; kout[idx] = res;
          } else {
            Vb[idx] = (__bf16)res; vout[idx] = res;
          }
        }
      }
    } else {
      #pragma unroll
      for (int i = 0; i < 4; i++) {
        #pragma unroll
        for (int r = 0; r < 4; r++) {
          int row = blockIdx.y * 128 + wm + i * 16 + hi * 4 + r;
          outp[(size_t)row * DM + n] = acc[i][j][r] + bv;
        }
      }
    }
  }
}

// ---------------- flash attention ----------------
// LDS tiles are [128 rows][256B rows], chunk-swizzled: chunk' = chunk ^ (row&7).
// Staged via global_load_lds (linear dest) with inverse-swizzled global source.

__device__ __forceinline__ void stage_swz(const __bf16* g, int rstride,
                                          __bf16* lds, int tid) {
  const int wave = tid >> 6, lane = tid & 63;
  const char* gb = (const char*)g;
  char* lb = (char*)lds;
  #pragma unroll
  for (int j = 0; j < 8; j++) {
    int off = j * 4096 + wave * 1024;               // wave-uniform LDS base
    int r = (off >> 8) + (lane >> 4);
    int c = lane & 15;
    const char* gs = gb + (size_t)r * (rstride * 2) + ((c ^ (r & 7)) << 4);
    async_copy16(gs, lb + off);
  }
}

__device__ __forceinline__ bf16x8 lds_frag(const __bf16* base, int row, int chunk) {
  return *reinterpret_cast<const bf16x8*>(
      reinterpret_cast<const char*>(base) + row * 256 + ((chunk ^ (row & 7)) << 4));
}

__global__ __launch_bounds__(256, 1) void attn_fwd(
    const __bf16* __restrict__ Qb, const __bf16* __restrict__ Kb,
    const __bf16* __restrict__ Vtb, __bf16* __restrict__ att_out) {
  __shared__ __bf16 Qs[128 * 128];
  __shared__ __bf16 Ks[128 * 128];
  __shared__ __bf16 Vts[128 * 128];
  __shared__ __bf16 Ps[4 * 32 * 128];   // per-wave P tile [32 q][128 s]
  const int tid = threadIdx.x, lane = tid & 63, wave = tid >> 6;
  const int hi = lane >> 4, lo = lane & 15;
  const int bh = blockIdx.y, b = bh >> 4, h = bh & 15;
  const __bf16* Qg = Qb + (size_t)bh * T_SEQ * DH;
  const __bf16* Kg = Kb + (size_t)bh * T_SEQ * DH;
  const __bf16* Vg = Vtb + (size_t)bh * DH * T_SEQ;
  const float scale = 0.08838834764831845f;   // 1/sqrt(128)
  const float L2E = 1.4426950408889634f;

  for (int pass = 0; pass < 2; ++pass) {
    int qi = pass ? (15 - blockIdx.x) : blockIdx.x;
    int q0 = qi * 128;
    __syncthreads();                           // all waves done with prev pass LDS
    stage_swz(Qg + (size_t)q0 * DH, DH, Qs, tid);
    f32x4 oacc[8][2] = {};
    float m0 = -3e38f, m1 = -3e38f, l0 = 0.f, l1 = 0.f;
    const int qgl0 = q0 + wave * 32 + lo;
    const int qgl1 = qgl0 + 16;

    for (int kt = 0; kt <= qi; ++kt) {
      __syncthreads();                         // prev tile reads done
      stage_swz(Kg + (size_t)kt * 128 * DH, DH, Ks, tid);
      stage_swz(Vg + (size_t)kt * 128, T_SEQ, Vts, tid);
      __syncthreads();                         // drains vmcnt(0): K/V (and Q) ready

      // S^T = K · Q^T : A = K[s][d], B = Q^T[d][q]; C: row=s (hi*4+r), col=q (lo)
      f32x4 sacc[8][2] = {};
      #pragma unroll
      for (int ks = 0; ks < 4; ++ks) {
        bf16x8 bq0 = lds_frag(Qs, wave * 32 + lo, ks * 4 + hi);
        bf16x8 bq1 = lds_frag(Qs, wave * 32 + 16 + lo, ks * 4 + hi);
        #pragma unroll
        for (int sf = 0; sf < 8; ++sf) {
          bf16x8 ak = lds_frag(Ks, sf * 16 + lo, ks * 4 + hi);
          sacc[sf][0] = MFMA16(ak, bq0, sacc[sf][0], 0, 0, 0);
          sacc[sf][1] = MFMA16(ak, bq1, sacc[sf][1], 0, 0, 0);
        }
      }
      const bool diag = (kt == qi);
      #pragma unroll
      for (int qf = 0; qf < 2; ++qf) {
        const int qgl = qf ? qgl1 : qgl0;
        float mold = qf ? m1 : m0;
        float mx = -3e38f;
        #pragma unroll
        for (int sf = 0; sf < 8; ++sf)
          #pragma unroll
          for (int r = 0; r < 4; ++r) {
            float v = sacc[sf][qf][r] * scale;
            if (diag && (kt * 128 + sf * 16 + hi * 4 + r) > qgl) v = -3e38f;
            sacc[sf][qf][r] = v;
            mx = fmaxf(mx, v);
          }
        mx = fmaxf(mx, __shfl_xor(mx, 16, 64));
        mx = fmaxf(mx, __shfl_xor(mx, 32, 64));
        float mnew = fmaxf(mold, mx);
        float alpha = __builtin_exp2f((mold - mnew) * L2E);
        if (qf) m1 = mnew; else m0 = mnew;
        float rs = 0.f;
        #pragma unroll
        for (int sf = 0; sf < 8; ++sf)
          #pragma unroll
          for (int r = 0; r < 4; ++r) {
            float p = __builtin_exp2f((sacc[sf][qf][r] - mnew) * L2E);
            sacc[sf][qf][r] = p;
            rs += p;
          }
        rs += __shfl_xor(rs, 16, 64);
        rs += __shfl_xor(rs, 32, 64);
        if (qf) l1 = l1 * alpha + rs; else l0 = l0 * alpha + rs;
        #pragma unroll
        for (int df = 0; df < 8; ++df) {
          oacc[df][qf][0] *= alpha; oacc[df][qf][1] *= alpha;
          oacc[df][qf][2] *= alpha; oacc[df][qf][3] *= alpha;
        }
        // write P tile: lane's 4 vals are contiguous s at row q_loc -> one b64
        const int q_loc = qf * 16 + lo;
        #pragma unroll
        for (int sf = 0; sf < 8; ++sf) {
          bf16x4 pk;
          pk[0] = (__bf16)sacc[sf][qf][0]; pk[1] = (__bf16)sacc[sf][qf][1];
          pk[2] = (__bf16)sacc[sf][qf][2]; pk[3] = (__bf16)sacc[sf][qf][3];
          int cb = sf * 32 + hi * 8;
          int chunk = cb >> 4, rem = cb & 15;
          char* p = (char*)Ps + wave * 8192 + q_loc * 256 +
                    (((chunk ^ (q_loc & 7)) << 4) | rem);
          *reinterpret_cast<bf16x4*>(p) = pk;
        }
      }
      // PV: O^T += V^T · P^T : A = V^T[d][s] (Vts rows), B = P[q][s] rows
      const __bf16* Pw = Ps + wave * 4096;
      #pragma unroll
      for (int ks = 0; ks < 4; ++ks) {
        bf16x8 bp0 = lds_frag(Pw, lo, ks * 4 + hi);
        bf16x8 bp1 = lds_frag(Pw, 16 + lo, ks * 4 + hi);
        #pragma unroll
        for (int df = 0; df < 8; ++df) {
          bf16x8 av = lds_frag(Vts, df * 16 + lo, ks * 4 + hi);
          oacc[df][0] = MFMA16(av, bp0, oacc[df][0], 0, 0, 0);
          oacc[df][1] = MFMA16(av, bp1, oacc[df][1], 0, 0, 0);
        }
      }
    } // kt

    // epilogue: O^T lane holds d = df*16 + hi*4 + r, q = qf*16 + lo
    #pragma unroll
    for (int qf = 0; qf < 2; ++qf) {
      float inv = 1.0f / (qf ? l1 : l0);
      int qrow = b * T_SEQ + q0 + wave * 32 + qf * 16 + lo;
      #pragma unroll
      for (int df = 0; df < 8; ++df) {
        bf16x4 pk;
        pk[0] = (__bf16)(oacc[df][qf][0] * inv);
        pk[1] = (__bf16)(oacc[df][qf][1] * inv);
        pk[2] = (__bf16)(oacc[df][qf][2] * inv);
        pk[3] = (__bf16)(oacc[df][qf][3] * inv);
        int d = df * 16 + hi * 4;
        *reinterpret_cast<bf16x4*>(att_out + (size_t)qrow * DM + h * DH + d) = pk;
      }
    }
  } // pass
}

// ---------------- launch ----------------

extern "C" void kernel_launch(void* const* d_in, const int* in_sizes, int n_in,
                              void* d_out, int out_size, void* d_ws, size_t ws_size,
                              hipStream_t stream) {
  const float* x     = (const float*)d_in[0];
  // d_in[1] = causal mask: ignored (mask applied analytically)
  const float* fcos  = (const float*)d_in[2];
  const float* fsin  = (const float*)d_in[3];
  const float* Wqkv  = (const float*)d_in[4];
  const float* bqkv  = (const float*)d_in[5];
  const float* Wproj = (const float*)d_in[6];
  const float* bproj = (const float*)d_in[7];
  float* out  = (float*)d_out;
  float* kout = out + (size_t)8388608;
  float* vout = out + (size_t)16777216;

  char* ws = (char*)d_ws;
  __bf16* xb     = (__bf16*)(ws);                 // 16 MiB; reused as att_out later
  __bf16* WqkvT  = (__bf16*)(ws + 16777216);      // 24 MiB
  __bf16* WprojT = (__bf16*)(ws + 41943040);      // 8 MiB
  __bf16* Qb     = (__bf16*)(ws + 50331648);      // 16 MiB
  __bf16* Kb     = (__bf16*)(ws + 67108864);      // 16 MiB
  __bf16* Vb     = (__bf16*)(ws + 83886080);      // 16 MiB
  __bf16* Vtb    = (__bf16*)(ws + 100663296);     // 16 MiB  (total 112 MiB)
  __bf16* att    = xb;                            // alias: xb dead after gemm1

  cast_bf16_k<<<8192, 256, 0, stream>>>(x, xb);
  transpose_cast_w<<<dim3(192, 64), dim3(32, 8), 0, stream>>>(Wqkv, WqkvT, DM, 3 * DM);
  transpose_cast_w<<<dim3(64, 64), dim3(32, 8), 0, stream>>>(Wproj, WprojT, DM, DM);
  // QKV: M=4096 (by 0..31), N=6144 (bx 0..47) -> 1536 blocks, ~1.5 rounds of 4/CU
  gemm_bt<1><<<dim3(48, 32), 256, 0, stream>>>(xb, WqkvT, DM, bqkv, fcos, fsin,
                                               Qb, Kb, Vb, kout, vout, nullptr);
  transpose_v<<<dim3(64, 4, NBH), dim3(32, 8), 0, stream>>>(Vb, Vtb);
  attn_fwd<<<dim3(8, NBH), 256, 0, stream>>>(Qb, Kb, Vtb, att);
  // proj: M=4096, N=2048 -> 16x32 = 512 blocks
  gemm_bt<0><<<dim3(16, 32), 256, 0, stream>>>(att, WprojT, DM, bproj, nullptr, nullptr,
                                               nullptr, nullptr, nullptr, nullptr, nullptr, out);
}

// Round 6
// 311.519 us; speedup vs baseline: 1.1884x; 1.1884x over previous
//
#include <hip/hip_runtime.h>
#include <hip/hip_bf16.h>

#define T_SEQ 2048
#define DM    2048
#define NH    16
#define DH    128
#define NBH   32          // B * NH
#define MROWS 4096        // B * T

typedef __bf16 bf16x8 __attribute__((ext_vector_type(8)));
typedef __bf16 bf16x4 __attribute__((ext_vector_type(4)));
typedef float  f32x4  __attribute__((ext_vector_type(4)));

#define MFMA16 __builtin_amdgcn_mfma_f32_16x16x32_bf16

__device__ __forceinline__ void async_copy16(const void* g, void* l) {
  __builtin_amdgcn_global_load_lds((const __attribute__((address_space(1))) void*)g,
                                   (__attribute__((address_space(3))) void*)l, 16, 0, 0);
}

// ---------------- prep kernels ----------------

__global__ void cast_bf16_k(const float* __restrict__ x, __bf16* __restrict__ xb) {
  int i = (blockIdx.x * 256 + threadIdx.x) * 4;
  float4 v = *reinterpret_cast<const float4*>(x + i);
  bf16x4 o;
  o[0] = (__bf16)v.x; o[1] = (__bf16)v.y; o[2] = (__bf16)v.z; o[3] = (__bf16)v.w;
  *reinterpret_cast<bf16x4*>(xb + i) = o;
}

// W [K][N] f32 -> WT [N][K] bf16
__global__ void transpose_cast_w(const float* __restrict__ W, __bf16* __restrict__ WT,
                                 int K, int N) {
  __shared__ float tile[32][33];
  int n0 = blockIdx.x * 32, k0 = blockIdx.y * 32;
  int tx = threadIdx.x, ty = threadIdx.y;
  #pragma unroll
  for (int i = 0; i < 4; i++)
    tile[ty + i * 8][tx] = W[(size_t)(k0 + ty + i * 8) * N + n0 + tx];
  __syncthreads();
  #pragma unroll
  for (int i = 0; i < 4; i++)
    WT[(size_t)(n0 + ty + i * 8) * K + k0 + tx] = (__bf16)tile[tx][ty + i * 8];
}

// Vb [BH][T][D] bf16 -> Vtb [BH][D][T] bf16
__global__ void transpose_v(const __bf16* __restrict__ Vb, __bf16* __restrict__ Vtb) {
  __shared__ __bf16 tile[32][34];
  int t0 = blockIdx.x * 32, d0 = blockIdx.y * 32, bh = blockIdx.z;
  const __bf16* src = Vb + (size_t)bh * T_SEQ * DH;
  __bf16* dst = Vtb + (size_t)bh * DH * T_SEQ;
  int tx = threadIdx.x, ty = threadIdx.y;
  #pragma unroll
  for (int i = 0; i < 4; i++)
    tile[ty + i * 8][tx] = src[(size_t)(t0 + ty + i * 8) * DH + d0 + tx];
  __syncthreads();
  #pragma unroll
  for (int i = 0; i < 4; i++)
    dst[(size_t)(d0 + ty + i * 8) * T_SEQ + t0 + tx] = tile[tx][ty + i * 8];
}

// ------- GEMM (C = A * Bt^T), BM=BN=128, BK=64, 4 waves, 1 barrier/K-tile -------
// LDS tile [128 rows][64 bf16] = 128-B rows, chunk-XOR swizzled (R4-verified).
// Epilogue: chunked LDS transpose -> per-thread 16 consecutive cols of one row
// -> register-adjacent RoPE pairs, coalesced float4 loads/stores (no RFO).

__device__ __forceinline__ bf16x8 rds(const __bf16* base, int row, int chunk) {
  return *reinterpret_cast<const bf16x8*>(
      reinterpret_cast<const char*>(base) + row * 128 + ((chunk ^ (row & 7)) << 4));
}

// stage one 128x64 tile (16 KB): 4 global_load_lds per wave
__device__ __forceinline__ void stage64(const __bf16* g, int K, int kt, char* lds,
                                        int wave, int lane) {
  #pragma unroll
  for (int j = 0; j < 4; j++) {
    int r = wave * 32 + j * 8 + (lane >> 3);
    int c = lane & 7;
    const char* src = (const char*)g + (size_t)r * (K * 2) + kt * 128 + ((c ^ (r & 7)) << 4);
    async_copy16(src, lds + wave * 4096 + j * 1024);
  }
}

template <int EPI>
__global__ __launch_bounds__(256, 2) void gemm_bt(
    const __bf16* __restrict__ A, const __bf16* __restrict__ Bt, int K,
    const float* __restrict__ bias,
    const float* __restrict__ fcos, const float* __restrict__ fsin,
    __bf16* __restrict__ Qb, __bf16* __restrict__ Kb, __bf16* __restrict__ Vb,
    float* __restrict__ kout, float* __restrict__ vout,
    float* __restrict__ outp) {
  __shared__ __align__(16) char smem[65536];   // K-loop: A0,A1,B0,B1; epilogue: f32 scratch
  const int tid = threadIdx.x, lane = tid & 63, wave = tid >> 6;
  const int hi = lane >> 4, lo = lane & 15;
  const int wm = (wave >> 1) * 64, wn = (wave & 1) * 64;
  const __bf16* Ab = A + (size_t)blockIdx.y * 128 * K;
  const __bf16* Bb = Bt + (size_t)blockIdx.x * 128 * K;
  f32x4 acc[4][4] = {};
  const int NK = K >> 6;

  stage64(Ab, K, 0, smem, wave, lane);
  stage64(Bb, K, 0, smem + 32768, wave, lane);
  __syncthreads();   // drains vmcnt: tile 0 ready

  for (int t = 0; t < NK; ++t) {
    const int sel = (t & 1) ? 16384 : 0;
    const __bf16* Ac = (const __bf16*)(smem + sel);
    const __bf16* Bc = (const __bf16*)(smem + 32768 + sel);
    if (t + 1 < NK) {
      stage64(Ab, K, t + 1, smem + (sel ^ 16384), wave, lane);
      stage64(Bb, K, t + 1, smem + 32768 + (sel ^ 16384), wave, lane);
    }
    bf16x8 a0[4], b0[4], a1[4], b1[4];
    #pragma unroll
    for (int m = 0; m < 4; ++m) a0[m] = rds(Ac, wm + m * 16 + lo, hi);
    #pragma unroll
    for (int n = 0; n < 4; ++n) b0[n] = rds(Bc, wn + n * 16 + lo, hi);
    __builtin_amdgcn_s_setprio(1);
    #pragma unroll
    for (int m = 0; m < 4; ++m)
      #pragma unroll
      for (int n = 0; n < 4; ++n)
        acc[m][n] = MFMA16(a0[m], b0[n], acc[m][n], 0, 0, 0);
    __builtin_amdgcn_s_setprio(0);
    #pragma unroll
    for (int m = 0; m < 4; ++m) a1[m] = rds(Ac, wm + m * 16 + lo, 4 + hi);
    #pragma unroll
    for (int n = 0; n < 4; ++n) b1[n] = rds(Bc, wn + n * 16 + lo, 4 + hi);
    __builtin_amdgcn_s_setprio(1);
    #pragma unroll
    for (int m = 0; m < 4; ++m)
      #pragma unroll
      for (int n = 0; n < 4; ++n)
        acc[m][n] = MFMA16(a1[m], b1[n], acc[m][n], 0, 0, 0);
    __builtin_amdgcn_s_setprio(0);
    __syncthreads();   // all reads of cur done; staging drains via implicit vmcnt(0)
  }

  // ---- chunked LDS-transpose epilogue ----
  float* sc = (float*)smem;            // [32][132] f32 = 16.9 KB (aliases K-loop LDS)
  const int rl_r = tid >> 3;           // read row 0..31
  const int cb   = (tid & 7) * 16;     // read col block (16 consecutive)
  #pragma unroll
  for (int cc = 0; cc < 4; ++cc) {
    __syncthreads();                   // LDS free / prev chunk consumed
    if ((wave >> 1) == (cc >> 1)) {    // waves owning this 32-row chunk write it
      #pragma unroll
      for (int mm = 0; mm < 2; ++mm) {
        int m = (cc & 1) * 2 + mm;
        #pragma unroll
        for (int j = 0; j < 4; ++j) {
          int col = wn + j * 16 + lo;
          int rl = mm * 16 + hi * 4;
          #pragma unroll
          for (int r = 0; r < 4; ++r)
            sc[(rl + r) * 132 + col] = acc[m][j][r];
        }
      }
    }
    __syncthreads();
    float v[16];
    #pragma unroll
    for (int q = 0; q < 4; ++q)
      *reinterpret_cast<float4*>(&v[q * 4]) =
          *reinterpret_cast<const float4*>(&sc[rl_r * 132 + cb + q * 4]);
    const int row = blockIdx.y * 128 + cc * 32 + rl_r;
    const int n0  = blockIdx.x * 128 + cb;
    #pragma unroll
    for (int q = 0; q < 4; ++q) {
      float4 bv = *reinterpret_cast<const float4*>(&bias[n0 + q * 4]);
      v[q * 4 + 0] += bv.x; v[q * 4 + 1] += bv.y;
      v[q * 4 + 2] += bv.z; v[q * 4 + 3] += bv.w;
    }
    if (EPI == 1) {
      const int which = n0 >> 11;              // block-uniform (tile inside one of Q/K/V)
      const int wn2 = n0 & 2047, h = wn2 >> 7, d0 = wn2 & 127;
      const int b = row >> 11, tt = row & 2047;
      if (which < 2) {                         // RoPE: pairs are register-adjacent
        const float* cp = fcos + tt * 64 + (d0 >> 1);
        const float* sp = fsin + tt * 64 + (d0 >> 1);
        float4 c0 = *reinterpret_cast<const float4*>(cp);
        float4 c1 = *reinterpret_cast<const float4*>(cp + 4);
        float4 s0 = *reinterpret_cast<const float4*>(sp);
        float4 s1 = *reinterpret_cast<const float4*>(sp + 4);
        float cs[8] = {c0.x, c0.y, c0.z, c0.w, c1.x, c1.y, c1.z, c1.w};
        float sn[8] = {s0.x, s0.y, s0.z, s0.w, s1.x, s1.y, s1.z, s1.w};
        #pragma unroll
        for (int p = 0; p < 8; ++p) {
          float re = v[2 * p], im = v[2 * p + 1];
          v[2 * p]     = re * cs[p] - im * sn[p];
          v[2 * p + 1] = re * sn[p] + im * cs[p];
        }
      }
      size_t base = (((size_t)(b * NH + h)) * T_SEQ + tt) * DH + d0;
      bf16x8 o0, o1;
      #pragma unroll
      for (int p = 0; p < 8; ++p) { o0[p] = (__bf16)v[p]; o1[p] = (__bf16)v[8 + p]; }
      if (which == 0) {
        *reinterpret_cast<bf16x8*>(Qb + base) = o0;
        *reinterpret_cast<bf16x8*>(Qb + base + 8) = o1;
      } else if (which == 1) {
        *reinterpret_cast<bf16x8*>(Kb + base) = o0;
        *reinterpret_cast<bf16x8*>(Kb + base + 8) = o1;
        #pragma unroll
        for (int q = 0; q < 4; ++q)
          *reinterpret_cast<float4*>(kout + base + q * 4) =
              *reinterpret_cast<const float4*>(&v[q * 4]);
      } else {
        *reinterpret_cast<bf16x8*>(Vb + base) = o0;
        *reinterpret_cast<bf16x8*>(Vb + base + 8) = o1;
        #pragma unroll
        for (int q = 0; q < 4; ++q)
          *reinterpret_cast<float4*>(vout + base + q * 4) =
              *reinterpret_cast<const float4*>(&v[q * 4]);
      }
    } else {
      float* op = outp + (size_t)row * DM + n0;
      #pragma unroll
      for (int q = 0; q < 4; ++q)
        *reinterpret_cast<float4*>(op + q * 4) =
            *reinterpret_cast<const float4*>(&v[q * 4]);
    }
  }
}

// ---------------- flash attention ----------------
// LDS tiles are [128 rows][256B rows], chunk-swizzled: chunk' = chunk ^ (row&7).
// Staged via global_load_lds (linear dest) with inverse-swizzled global source.

__device__ __forceinline__ void stage_swz(const __bf16* g, int rstride,
                                          __bf16* lds, int tid) {
  const int wave = tid >> 6, lane = tid & 63;
  const char* gb = (const char*)g;
  char* lb = (char*)lds;
  #pragma unroll
  for (int j = 0; j < 8; j++) {
    int off = j * 4096 + wave * 1024;               // wave-uniform LDS base
    int r = (off >> 8) + (lane >> 4);
    int c = lane & 15;
    const char* gs = gb + (size_t)r * (rstride * 2) + ((c ^ (r & 7)) << 4);
    async_copy16(gs, lb + off);
  }
}

__device__ __forceinline__ bf16x8 lds_frag(const __bf16* base, int row, int chunk) {
  return *reinterpret_cast<const bf16x8*>(
      reinterpret_cast<const char*>(base) + row * 256 + ((chunk ^ (row & 7)) << 4));
}

__global__ __launch_bounds__(256, 1) void attn_fwd(
    const __bf16* __restrict__ Qb, const __bf16* __restrict__ Kb,
    const __bf16* __restrict__ Vtb, __bf16* __restrict__ att_out) {
  __shared__ __bf16 Qs[128 * 128];
  __shared__ __bf16 Ks[128 * 128];
  __shared__ __bf16 Vts[128 * 128];
  __shared__ __bf16 Ps[4 * 32 * 128];   // per-wave P tile [32 q][128 s]
  const int tid = threadIdx.x, lane = tid & 63, wave = tid >> 6;
  const int hi = lane >> 4, lo = lane & 15;
  const int bh = blockIdx.y, b = bh >> 4, h = bh & 15;
  const __bf16* Qg = Qb + (size_t)bh * T_SEQ * DH;
  const __bf16* Kg = Kb + (size_t)bh * T_SEQ * DH;
  const __bf16* Vg = Vtb + (size_t)bh * DH * T_SEQ;
  const float scale = 0.08838834764831845f;   // 1/sqrt(128)
  const float L2E = 1.4426950408889634f;

  for (int pass = 0; pass < 2; ++pass) {
    int qi = pass ? (15 - blockIdx.x) : blockIdx.x;
    int q0 = qi * 128;
    __syncthreads();                           // all waves done with prev pass LDS
    stage_swz(Qg + (size_t)q0 * DH, DH, Qs, tid);
    f32x4 oacc[8][2] = {};
    float m0 = -3e38f, m1 = -3e38f, l0 = 0.f, l1 = 0.f;
    const int qgl0 = q0 + wave * 32 + lo;
    const int qgl1 = qgl0 + 16;

    for (int kt = 0; kt <= qi; ++kt) {
      __syncthreads();                         // prev tile reads done
      stage_swz(Kg + (size_t)kt * 128 * DH, DH, Ks, tid);
      stage_swz(Vg + (size_t)kt * 128, T_SEQ, Vts, tid);
      __syncthreads();                         // drains vmcnt(0): K/V (and Q) ready

      // S^T = K · Q^T : A = K[s][d], B = Q^T[d][q]; C: row=s (hi*4+r), col=q (lo)
      f32x4 sacc[8][2] = {};
      #pragma unroll
      for (int ks = 0; ks < 4; ++ks) {
        bf16x8 bq0 = lds_frag(Qs, wave * 32 + lo, ks * 4 + hi);
        bf16x8 bq1 = lds_frag(Qs, wave * 32 + 16 + lo, ks * 4 + hi);
        #pragma unroll
        for (int sf = 0; sf < 8; ++sf) {
          bf16x8 ak = lds_frag(Ks, sf * 16 + lo, ks * 4 + hi);
          sacc[sf][0] = MFMA16(ak, bq0, sacc[sf][0], 0, 0, 0);
          sacc[sf][1] = MFMA16(ak, bq1, sacc[sf][1], 0, 0, 0);
        }
      }
      const bool diag = (kt == qi);
      #pragma unroll
      for (int qf = 0; qf < 2; ++qf) {
        const int qgl = qf ? qgl1 : qgl0;
        float mold = qf ? m1 : m0;
        float mx = -3e38f;
        #pragma unroll
        for (int sf = 0; sf < 8; ++sf)
          #pragma unroll
          for (int r = 0; r < 4; ++r) {
            float v = sacc[sf][qf][r] * scale;
            if (diag && (kt * 128 + sf * 16 + hi * 4 + r) > qgl) v = -3e38f;
            sacc[sf][qf][r] = v;
            mx = fmaxf(mx, v);
          }
        mx = fmaxf(mx, __shfl_xor(mx, 16, 64));
        mx = fmaxf(mx, __shfl_xor(mx, 32, 64));
        float mnew = fmaxf(mold, mx);
        float alpha = __builtin_exp2f((mold - mnew) * L2E);
        if (qf) m1 = mnew; else m0 = mnew;
        float rs = 0.f;
        #pragma unroll
        for (int sf = 0; sf < 8; ++sf)
          #pragma unroll
          for (int r = 0; r < 4; ++r) {
            float p = __builtin_exp2f((sacc[sf][qf][r] - mnew) * L2E);
            sacc[sf][qf][r] = p;
            rs += p;
          }
        rs += __shfl_xor(rs, 16, 64);
        rs += __shfl_xor(rs, 32, 64);
        if (qf) l1 = l1 * alpha + rs; else l0 = l0 * alpha + rs;
        #pragma unroll
        for (int df = 0; df < 8; ++df) {
          oacc[df][qf][0] *= alpha; oacc[df][qf][1] *= alpha;
          oacc[df][qf][2] *= alpha; oacc[df][qf][3] *= alpha;
        }
        // write P tile: lane's 4 vals are contiguous s at row q_loc -> one b64
        const int q_loc = qf * 16 + lo;
        #pragma unroll
        for (int sf = 0; sf < 8; ++sf) {
          bf16x4 pk;
          pk[0] = (__bf16)sacc[sf][qf][0]; pk[1] = (__bf16)sacc[sf][qf][1];
          pk[2] = (__bf16)sacc[sf][qf][2]; pk[3] = (__bf16)sacc[sf][qf][3];
          int cb = sf * 32 + hi * 8;
          int chunk = cb >> 4, rem = cb & 15;
          char* p = (char*)Ps + wave * 8192 + q_loc * 256 +
                    (((chunk ^ (q_loc & 7)) << 4) | rem);
          *reinterpret_cast<bf16x4*>(p) = pk;
        }
      }
      // PV: O^T += V^T · P^T : A = V^T[d][s] (Vts rows), B = P[q][s] rows
      const __bf16* Pw = Ps + wave * 4096;
      #pragma unroll
      for (int ks = 0; ks < 4; ++ks) {
        bf16x8 bp0 = lds_frag(Pw, lo, ks * 4 + hi);
        bf16x8 bp1 = lds_frag(Pw, 16 + lo, ks * 4 + hi);
        #pragma unroll
        for (int df = 0; df < 8; ++df) {
          bf16x8 av = lds_frag(Vts, df * 16 + lo, ks * 4 + hi);
          oacc[df][0] = MFMA16(av, bp0, oacc[df][0], 0, 0, 0);
          oacc[df][1] = MFMA16(av, bp1, oacc[df][1], 0, 0, 0);
        }
      }
    } // kt

    // epilogue: O^T lane holds d = df*16 + hi*4 + r, q = qf*16 + lo
    #pragma unroll
    for (int qf = 0; qf < 2; ++qf) {
      float inv = 1.0f / (qf ? l1 : l0);
      int qrow = b * T_SEQ + q0 + wave * 32 + qf * 16 + lo;
      #pragma unroll
      for (int df = 0; df < 8; ++df) {
        bf16x4 pk;
        pk[0] = (__bf16)(oacc[df][qf][0] * inv);
        pk[1] = (__bf16)(oacc[df][qf][1] * inv);
        pk[2] = (__bf16)(oacc[df][qf][2] * inv);
        pk[3] = (__bf16)(oacc[df][qf][3] * inv);
        int d = df * 16 + hi * 4;
        *reinterpret_cast<bf16x4*>(att_out + (size_t)qrow * DM + h * DH + d) = pk;
      }
    }
  } // pass
}

// ---------------- launch ----------------

extern "C" void kernel_launch(void* const* d_in, const int* in_sizes, int n_in,
                              void* d_out, int out_size, void* d_ws, size_t ws_size,
                              hipStream_t stream) {
  const float* x     = (const float*)d_in[0];
  // d_in[1] = causal mask: ignored (mask applied analytically)
  const float* fcos  = (const float*)d_in[2];
  const float* fsin  = (const float*)d_in[3];
  const float* Wqkv  = (const float*)d_in[4];
  const float* bqkv  = (const float*)d_in[5];
  const float* Wproj = (const float*)d_in[6];
  const float* bproj = (const float*)d_in[7];
  float* out  = (float*)d_out;
  float* kout = out + (size_t)8388608;
  float* vout = out + (size_t)16777216;

  char* ws = (char*)d_ws;
  __bf16* xb     = (__bf16*)(ws);                 // 16 MiB; reused as att_out later
  __bf16* WqkvT  = (__bf16*)(ws + 16777216);      // 24 MiB
  __bf16* WprojT = (__bf16*)(ws + 41943040);      // 8 MiB
  __bf16* Qb     = (__bf16*)(ws + 50331648);      // 16 MiB
  __bf16* Kb     = (__bf16*)(ws + 67108864);      // 16 MiB
  __bf16* Vb     = (__bf16*)(ws + 83886080);      // 16 MiB
  __bf16* Vtb    = (__bf16*)(ws + 100663296);     // 16 MiB  (total 112 MiB)
  __bf16* att    = xb;                            // alias: xb dead after gemm1

  cast_bf16_k<<<8192, 256, 0, stream>>>(x, xb);
  transpose_cast_w<<<dim3(192, 64), dim3(32, 8), 0, stream>>>(Wqkv, WqkvT, DM, 3 * DM);
  transpose_cast_w<<<dim3(64, 64), dim3(32, 8), 0, stream>>>(Wproj, WprojT, DM, DM);
  // QKV: M=4096 (by 0..31), N=6144 (bx 0..47) -> 1536 blocks
  gemm_bt<1><<<dim3(48, 32), 256, 0, stream>>>(xb, WqkvT, DM, bqkv, fcos, fsin,
                                               Qb, Kb, Vb, kout, vout, nullptr);
  transpose_v<<<dim3(64, 4, NBH), dim3(32, 8), 0, stream>>>(Vb, Vtb);
  attn_fwd<<<dim3(8, NBH), 256, 0, stream>>>(Qb, Kb, Vtb, att);
  // proj: M=4096, N=2048 -> 16x32 = 512 blocks
  gemm_bt<0><<<dim3(16, 32), 256, 0, stream>>>(att, WprojT, DM, bproj, nullptr, nullptr,
                                               nullptr, nullptr, nullptr, nullptr, nullptr, out);
}

// Round 7
// 301.025 us; speedup vs baseline: 1.2298x; 1.0349x over previous
//
#include <hip/hip_runtime.h>
#include <hip/hip_bf16.h>

#define T_SEQ 2048
#define DM    2048
#define NH    16
#define DH    128
#define NBH   32          // B * NH
#define MROWS 4096        // B * T

typedef __bf16 bf16x8 __attribute__((ext_vector_type(8)));
typedef __bf16 bf16x4 __attribute__((ext_vector_type(4)));
typedef float  f32x4  __attribute__((ext_vector_type(4)));

#define MFMA16 __builtin_amdgcn_mfma_f32_16x16x32_bf16

__device__ __forceinline__ void async_copy16(const void* g, void* l) {
  __builtin_amdgcn_global_load_lds((const __attribute__((address_space(1))) void*)g,
                                   (__attribute__((address_space(3))) void*)l, 16, 0, 0);
}

// ---------------- prep kernels ----------------

__global__ void cast_bf16_k(const float* __restrict__ x, __bf16* __restrict__ xb) {
  int i = (blockIdx.x * 256 + threadIdx.x) * 4;
  float4 v = *reinterpret_cast<const float4*>(x + i);
  bf16x4 o;
  o[0] = (__bf16)v.x; o[1] = (__bf16)v.y; o[2] = (__bf16)v.z; o[3] = (__bf16)v.w;
  *reinterpret_cast<bf16x4*>(xb + i) = o;
}

// W [K][N] f32 -> WT [N][K] bf16
__global__ void transpose_cast_w(const float* __restrict__ W, __bf16* __restrict__ WT,
                                 int K, int N) {
  __shared__ float tile[32][33];
  int n0 = blockIdx.x * 32, k0 = blockIdx.y * 32;
  int tx = threadIdx.x, ty = threadIdx.y;
  #pragma unroll
  for (int i = 0; i < 4; i++)
    tile[ty + i * 8][tx] = W[(size_t)(k0 + ty + i * 8) * N + n0 + tx];
  __syncthreads();
  #pragma unroll
  for (int i = 0; i < 4; i++)
    WT[(size_t)(n0 + ty + i * 8) * K + k0 + tx] = (__bf16)tile[tx][ty + i * 8];
}

// Vb [BH][T][D] bf16 -> Vtb [BH][D][T] bf16
__global__ void transpose_v(const __bf16* __restrict__ Vb, __bf16* __restrict__ Vtb) {
  __shared__ __bf16 tile[32][34];
  int t0 = blockIdx.x * 32, d0 = blockIdx.y * 32, bh = blockIdx.z;
  const __bf16* src = Vb + (size_t)bh * T_SEQ * DH;
  __bf16* dst = Vtb + (size_t)bh * DH * T_SEQ;
  int tx = threadIdx.x, ty = threadIdx.y;
  #pragma unroll
  for (int i = 0; i < 4; i++)
    tile[ty + i * 8][tx] = src[(size_t)(t0 + ty + i * 8) * DH + d0 + tx];
  __syncthreads();
  #pragma unroll
  for (int i = 0; i < 4; i++)
    dst[(size_t)(d0 + ty + i * 8) * T_SEQ + t0 + tx] = tile[tx][ty + i * 8];
}

// ------- GEMM (C = A * Bt^T), BM=BN=128, BK=64, 4 waves, 1 barrier/K-tile -------
// LDS tile [128 rows][64 bf16] = 128-B rows, chunk-XOR swizzled (R4-verified).
// Epilogue: chunked LDS transpose -> per-thread 16 consecutive cols of one row
// -> register-adjacent RoPE pairs, coalesced float4 loads/stores (no RFO).

__device__ __forceinline__ bf16x8 rds(const __bf16* base, int row, int chunk) {
  return *reinterpret_cast<const bf16x8*>(
      reinterpret_cast<const char*>(base) + row * 128 + ((chunk ^ (row & 7)) << 4));
}

// stage one 128x64 tile (16 KB): 4 global_load_lds per wave (256-thread blocks)
__device__ __forceinline__ void stage64(const __bf16* g, int K, int kt, char* lds,
                                        int wave, int lane) {
  #pragma unroll
  for (int j = 0; j < 4; j++) {
    int r = wave * 32 + j * 8 + (lane >> 3);
    int c = lane & 7;
    const char* src = (const char*)g + (size_t)r * (K * 2) + kt * 128 + ((c ^ (r & 7)) << 4);
    async_copy16(src, lds + wave * 4096 + j * 1024);
  }
}

template <int EPI>
__global__ __launch_bounds__(256, 2) void gemm_bt(
    const __bf16* __restrict__ A, const __bf16* __restrict__ Bt, int K,
    const float* __restrict__ bias,
    const float* __restrict__ fcos, const float* __restrict__ fsin,
    __bf16* __restrict__ Qb, __bf16* __restrict__ Kb, __bf16* __restrict__ Vb,
    float* __restrict__ kout, float* __restrict__ vout,
    float* __restrict__ outp) {
  __shared__ __align__(16) char smem[65536];   // K-loop: A0,A1,B0,B1; epilogue: f32 scratch
  const int tid = threadIdx.x, lane = tid & 63, wave = tid >> 6;
  const int hi = lane >> 4, lo = lane & 15;
  const int wm = (wave >> 1) * 64, wn = (wave & 1) * 64;
  const __bf16* Ab = A + (size_t)blockIdx.y * 128 * K;
  const __bf16* Bb = Bt + (size_t)blockIdx.x * 128 * K;
  f32x4 acc[4][4] = {};
  const int NK = K >> 6;

  stage64(Ab, K, 0, smem, wave, lane);
  stage64(Bb, K, 0, smem + 32768, wave, lane);
  __syncthreads();   // drains vmcnt: tile 0 ready

  for (int t = 0; t < NK; ++t) {
    const int sel = (t & 1) ? 16384 : 0;
    const __bf16* Ac = (const __bf16*)(smem + sel);
    const __bf16* Bc = (const __bf16*)(smem + 32768 + sel);
    if (t + 1 < NK) {
      stage64(Ab, K, t + 1, smem + (sel ^ 16384), wave, lane);
      stage64(Bb, K, t + 1, smem + 32768 + (sel ^ 16384), wave, lane);
    }
    bf16x8 a0[4], b0[4], a1[4], b1[4];
    #pragma unroll
    for (int m = 0; m < 4; ++m) a0[m] = rds(Ac, wm + m * 16 + lo, hi);
    #pragma unroll
    for (int n = 0; n < 4; ++n) b0[n] = rds(Bc, wn + n * 16 + lo, hi);
    __builtin_amdgcn_s_setprio(1);
    #pragma unroll
    for (int m = 0; m < 4; ++m)
      #pragma unroll
      for (int n = 0; n < 4; ++n)
        acc[m][n] = MFMA16(a0[m], b0[n], acc[m][n], 0, 0, 0);
    __builtin_amdgcn_s_setprio(0);
    #pragma unroll
    for (int m = 0; m < 4; ++m) a1[m] = rds(Ac, wm + m * 16 + lo, 4 + hi);
    #pragma unroll
    for (int n = 0; n < 4; ++n) b1[n] = rds(Bc, wn + n * 16 + lo, 4 + hi);
    __builtin_amdgcn_s_setprio(1);
    #pragma unroll
    for (int m = 0; m < 4; ++m)
      #pragma unroll
      for (int n = 0; n < 4; ++n)
        acc[m][n] = MFMA16(a1[m], b1[n], acc[m][n], 0, 0, 0);
    __builtin_amdgcn_s_setprio(0);
    __syncthreads();   // all reads of cur done; staging drains via implicit vmcnt(0)
  }

  // ---- chunked LDS-transpose epilogue ----
  float* sc = (float*)smem;            // [32][132] f32 = 16.9 KB (aliases K-loop LDS)
  const int rl_r = tid >> 3;           // read row 0..31
  const int cb   = (tid & 7) * 16;     // read col block (16 consecutive)
  #pragma unroll
  for (int cc = 0; cc < 4; ++cc) {
    __syncthreads();                   // LDS free / prev chunk consumed
    if ((wave >> 1) == (cc >> 1)) {    // waves owning this 32-row chunk write it
      #pragma unroll
      for (int mm = 0; mm < 2; ++mm) {
        int m = (cc & 1) * 2 + mm;
        #pragma unroll
        for (int j = 0; j < 4; ++j) {
          int col = wn + j * 16 + lo;
          int rl = mm * 16 + hi * 4;
          #pragma unroll
          for (int r = 0; r < 4; ++r)
            sc[(rl + r) * 132 + col] = acc[m][j][r];
        }
      }
    }
    __syncthreads();
    float v[16];
    #pragma unroll
    for (int q = 0; q < 4; ++q)
      *reinterpret_cast<float4*>(&v[q * 4]) =
          *reinterpret_cast<const float4*>(&sc[rl_r * 132 + cb + q * 4]);
    const int row = blockIdx.y * 128 + cc * 32 + rl_r;
    const int n0  = blockIdx.x * 128 + cb;
    #pragma unroll
    for (int q = 0; q < 4; ++q) {
      float4 bv = *reinterpret_cast<const float4*>(&bias[n0 + q * 4]);
      v[q * 4 + 0] += bv.x; v[q * 4 + 1] += bv.y;
      v[q * 4 + 2] += bv.z; v[q * 4 + 3] += bv.w;
    }
    if (EPI == 1) {
      const int which = n0 >> 11;              // block-uniform (tile inside one of Q/K/V)
      const int wn2 = n0 & 2047, h = wn2 >> 7, d0 = wn2 & 127;
      const int b = row >> 11, tt = row & 2047;
      if (which < 2) {                         // RoPE: pairs are register-adjacent
        const float* cp = fcos + tt * 64 + (d0 >> 1);
        const float* sp = fsin + tt * 64 + (d0 >> 1);
        float4 c0 = *reinterpret_cast<const float4*>(cp);
        float4 c1 = *reinterpret_cast<const float4*>(cp + 4);
        float4 s0 = *reinterpret_cast<const float4*>(sp);
        float4 s1 = *reinterpret_cast<const float4*>(sp + 4);
        float cs[8] = {c0.x, c0.y, c0.z, c0.w, c1.x, c1.y, c1.z, c1.w};
        float sn[8] = {s0.x, s0.y, s0.z, s0.w, s1.x, s1.y, s1.z, s1.w};
        #pragma unroll
        for (int p = 0; p < 8; ++p) {
          float re = v[2 * p], im = v[2 * p + 1];
          v[2 * p]     = re * cs[p] - im * sn[p];
          v[2 * p + 1] = re * sn[p] + im * cs[p];
        }
      }
      size_t base = (((size_t)(b * NH + h)) * T_SEQ + tt) * DH + d0;
      bf16x8 o0, o1;
      #pragma unroll
      for (int p = 0; p < 8; ++p) { o0[p] = (__bf16)v[p]; o1[p] = (__bf16)v[8 + p]; }
      if (which == 0) {
        *reinterpret_cast<bf16x8*>(Qb + base) = o0;
        *reinterpret_cast<bf16x8*>(Qb + base + 8) = o1;
      } else if (which == 1) {
        *reinterpret_cast<bf16x8*>(Kb + base) = o0;
        *reinterpret_cast<bf16x8*>(Kb + base + 8) = o1;
        #pragma unroll
        for (int q = 0; q < 4; ++q)
          *reinterpret_cast<float4*>(kout + base + q * 4) =
              *reinterpret_cast<const float4*>(&v[q * 4]);
      } else {
        *reinterpret_cast<bf16x8*>(Vb + base) = o0;
        *reinterpret_cast<bf16x8*>(Vb + base + 8) = o1;
        #pragma unroll
        for (int q = 0; q < 4; ++q)
          *reinterpret_cast<float4*>(vout + base + q * 4) =
              *reinterpret_cast<const float4*>(&v[q * 4]);
      }
    } else {
      float* op = outp + (size_t)row * DM + n0;
      #pragma unroll
      for (int q = 0; q < 4; ++q)
        *reinterpret_cast<float4*>(op + q * 4) =
            *reinterpret_cast<const float4*>(&v[q * 4]);
    }
  }
}

// ---------------- flash attention (512 threads, 8 waves x 16 q-rows) ----------------
// Qs [128][128] / Ks [64][128]: 256-B rows; Vts [128 d][64 s] / P [16][64]: 128-B
// rows. All chunk-XOR swizzled (chunk' = chunk ^ (row&7)); global_load_lds with
// inverse-swizzled global source; reads apply the same XOR.

__device__ __forceinline__ bf16x8 lds_frag(const __bf16* base, int row, int chunk) {
  return *reinterpret_cast<const bf16x8*>(
      reinterpret_cast<const char*>(base) + row * 256 + ((chunk ^ (row & 7)) << 4));
}

// stage NLOADS KB-per-wave of 256-B-row tile (512 threads): rows = NLOADS*32
template <int NLOADS>
__device__ __forceinline__ void stage256(const __bf16* g, __bf16* lds, int tid) {
  const int wave = tid >> 6, lane = tid & 63;
  #pragma unroll
  for (int j = 0; j < NLOADS; j++) {
    int off = j * 8192 + wave * 1024;
    int r = (off >> 8) + (lane >> 4);
    int c = lane & 15;
    const char* gs = (const char*)g + (size_t)r * 256 + ((c ^ (r & 7)) << 4);
    async_copy16(gs, (char*)lds + off);
  }
}

// stage V^T tile [128 d][64 s] (16 KB) from Vtb (row stride T_SEQ*2 B)
__device__ __forceinline__ void stage_vt(const __bf16* g, int kt, __bf16* lds, int tid) {
  const int wave = tid >> 6, lane = tid & 63;
  #pragma unroll
  for (int j = 0; j < 2; j++) {
    int off = j * 8192 + wave * 1024;
    int r = (off >> 7) + (lane >> 3);
    int c = lane & 7;
    const char* gs = (const char*)g + (size_t)r * (T_SEQ * 2) + kt * 128 + ((c ^ (r & 7)) << 4);
    async_copy16(gs, (char*)lds + off);
  }
}

__global__ __launch_bounds__(512, 2) void attn_fwd(
    const __bf16* __restrict__ Qb, const __bf16* __restrict__ Kb,
    const __bf16* __restrict__ Vtb, __bf16* __restrict__ att_out) {
  __shared__ __bf16 Qs[128 * 128];   // 32 KB
  __shared__ __bf16 Ks[64 * 128];    // 16 KB
  __shared__ __bf16 Vts[128 * 64];   // 16 KB
  __shared__ __bf16 Ps[8 * 16 * 64]; // 16 KB (per-wave [16 q][64 s])
  const int tid = threadIdx.x, lane = tid & 63, wave = tid >> 6;
  const int hi = lane >> 4, lo = lane & 15;
  const int bh = blockIdx.y, b = bh >> 4, h = bh & 15;
  const __bf16* Qg = Qb + (size_t)bh * T_SEQ * DH;
  const __bf16* Kg = Kb + (size_t)bh * T_SEQ * DH;
  const __bf16* Vg = Vtb + (size_t)bh * DH * T_SEQ;
  const float scale = 0.08838834764831845f;   // 1/sqrt(128)
  const float L2E = 1.4426950408889634f;
  __bf16* Pw = Ps + wave * 1024;

  for (int pass = 0; pass < 2; ++pass) {
    const int qi = pass ? (15 - blockIdx.x) : blockIdx.x;
    const int q0 = qi * 128;
    __syncthreads();                          // prev pass LDS reads done
    stage256<4>(Qg + (size_t)q0 * DH, Qs, tid);
    f32x4 oacc[8] = {};
    float m = -3e38f, l = 0.f;
    const int qg = q0 + wave * 16 + lo;       // this lane's q row
    const int NT = 2 * qi + 2;

    for (int kt = 0; kt < NT; ++kt) {
      __syncthreads();                        // prev tile reads done
      stage256<2>(Kg + (size_t)kt * 64 * DH, Ks, tid);
      stage_vt(Vg, kt, Vts, tid);
      __syncthreads();                        // drains vmcnt(0): Q/K/V ready

      // S^T = K · Q^T : A = K[s][d], B = Q^T[d][q]; C: row=s (hi*4+r), col=q (lo)
      f32x4 sacc[4] = {};
      #pragma unroll
      for (int ks = 0; ks < 4; ++ks) {
        bf16x8 bq = lds_frag(Qs, wave * 16 + lo, ks * 4 + hi);
        #pragma unroll
        for (int sf = 0; sf < 4; ++sf) {
          bf16x8 ak = lds_frag(Ks, sf * 16 + lo, ks * 4 + hi);
          sacc[sf] = MFMA16(ak, bq, sacc[sf], 0, 0, 0);
        }
      }
      const bool maskt = (kt * 64 + 63) > (q0 + wave * 16);
      float mx = -3e38f;
      #pragma unroll
      for (int sf = 0; sf < 4; ++sf)
        #pragma unroll
        for (int r = 0; r < 4; ++r) {
          float v = sacc[sf][r] * scale;
          if (maskt && (kt * 64 + sf * 16 + hi * 4 + r) > qg) v = -3e38f;
          sacc[sf][r] = v;
          mx = fmaxf(mx, v);
        }
      mx = fmaxf(mx, __shfl_xor(mx, 16, 64));
      mx = fmaxf(mx, __shfl_xor(mx, 32, 64));
      // defer-max (T13): skip O-rescale when tile max doesn't exceed m by >8
      const bool nr = __all(mx - m <= 8.0f);
      if (!nr) {
        float mnew = fmaxf(m, mx);
        float alpha = __builtin_exp2f((m - mnew) * L2E);
        m = mnew;
        l *= alpha;
        #pragma unroll
        for (int df = 0; df < 8; ++df) {
          oacc[df][0] *= alpha; oacc[df][1] *= alpha;
          oacc[df][2] *= alpha; oacc[df][3] *= alpha;
        }
      }
      float rs = 0.f;
      #pragma unroll
      for (int sf = 0; sf < 4; ++sf)
        #pragma unroll
        for (int r = 0; r < 4; ++r) {
          float p = __builtin_exp2f((sacc[sf][r] - m) * L2E);
          sacc[sf][r] = p;
          rs += p;
        }
      rs += __shfl_xor(rs, 16, 64);
      rs += __shfl_xor(rs, 32, 64);
      l += rs;
      // write P tile: lane's 4 vals are contiguous s at row lo -> one b64
      #pragma unroll
      for (int sf = 0; sf < 4; ++sf) {
        bf16x4 pk;
        pk[0] = (__bf16)sacc[sf][0]; pk[1] = (__bf16)sacc[sf][1];
        pk[2] = (__bf16)sacc[sf][2]; pk[3] = (__bf16)sacc[sf][3];
        int byte = sf * 32 + hi * 8;
        int chunk = byte >> 4, rem = byte & 15;
        char* p = (char*)Pw + lo * 128 + (((chunk ^ (lo & 7)) << 4) | rem);
        *reinterpret_cast<bf16x4*>(p) = pk;
      }
      // PV: O^T += V^T · P^T : A = V^T[d][s] (Vts rows), B = P[q][s] rows
      #pragma unroll
      for (int ks = 0; ks < 2; ++ks) {
        bf16x8 bp = rds(Pw, lo, ks * 4 + hi);
        #pragma unroll
        for (int df = 0; df < 8; ++df) {
          bf16x8 av = rds(Vts, df * 16 + lo, ks * 4 + hi);
          oacc[df] = MFMA16(av, bp, oacc[df], 0, 0, 0);
        }
      }
    } // kt

    // epilogue: O^T lane holds d = df*16 + hi*4 + r, q = lo (wave's 16 rows)
    float inv = 1.0f / l;
    int qrow = b * T_SEQ + q0 + wave * 16 + lo;
    #pragma unroll
    for (int df = 0; df < 8; ++df) {
      bf16x4 pk;
      pk[0] = (__bf16)(oacc[df][0] * inv);
      pk[1] = (__bf16)(oacc[df][1] * inv);
      pk[2] = (__bf16)(oacc[df][2] * inv);
      pk[3] = (__bf16)(oacc[df][3] * inv);
      int d = df * 16 + hi * 4;
      *reinterpret_cast<bf16x4*>(att_out + (size_t)qrow * DM + h * DH + d) = pk;
    }
  } // pass
}

// ---------------- launch ----------------

extern "C" void kernel_launch(void* const* d_in, const int* in_sizes, int n_in,
                              void* d_out, int out_size, void* d_ws, size_t ws_size,
                              hipStream_t stream) {
  const float* x     = (const float*)d_in[0];
  // d_in[1] = causal mask: ignored (mask applied analytically)
  const float* fcos  = (const float*)d_in[2];
  const float* fsin  = (const float*)d_in[3];
  const float* Wqkv  = (const float*)d_in[4];
  const float* bqkv  = (const float*)d_in[5];
  const float* Wproj = (const float*)d_in[6];
  const float* bproj = (const float*)d_in[7];
  float* out  = (float*)d_out;
  float* kout = out + (size_t)8388608;
  float* vout = out + (size_t)16777216;

  char* ws = (char*)d_ws;
  __bf16* xb     = (__bf16*)(ws);                 // 16 MiB; reused as att_out later
  __bf16* WqkvT  = (__bf16*)(ws + 16777216);      // 24 MiB
  __bf16* WprojT = (__bf16*)(ws + 41943040);      // 8 MiB
  __bf16* Qb     = (__bf16*)(ws + 50331648);      // 16 MiB
  __bf16* Kb     = (__bf16*)(ws + 67108864);      // 16 MiB
  __bf16* Vb     = (__bf16*)(ws + 83886080);      // 16 MiB
  __bf16* Vtb    = (__bf16*)(ws + 100663296);     // 16 MiB  (total 112 MiB)
  __bf16* att    = xb;                            // alias: xb dead after gemm1

  cast_bf16_k<<<8192, 256, 0, stream>>>(x, xb);
  transpose_cast_w<<<dim3(192, 64), dim3(32, 8), 0, stream>>>(Wqkv, WqkvT, DM, 3 * DM);
  transpose_cast_w<<<dim3(64, 64), dim3(32, 8), 0, stream>>>(Wproj, WprojT, DM, DM);
  // QKV: M=4096 (by 0..31), N=6144 (bx 0..47) -> 1536 blocks
  gemm_bt<1><<<dim3(48, 32), 256, 0, stream>>>(xb, WqkvT, DM, bqkv, fcos, fsin,
                                               Qb, Kb, Vb, kout, vout, nullptr);
  transpose_v<<<dim3(64, 4, NBH), dim3(32, 8), 0, stream>>>(Vb, Vtb);
  attn_fwd<<<dim3(8, NBH), 512, 0, stream>>>(Qb, Kb, Vtb, att);
  // proj: M=4096, N=2048 -> 16x32 = 512 blocks
  gemm_bt<0><<<dim3(16, 32), 256, 0, stream>>>(att, WprojT, DM, bproj, nullptr, nullptr,
                                               nullptr, nullptr, nullptr, nullptr, nullptr, out);
}

// Round 9
// 281.642 us; speedup vs baseline: 1.3145x; 1.0688x over previous
//
#include <hip/hip_runtime.h>
#include <hip/hip_bf16.h>

#define T_SEQ 2048
#define DM    2048
#define NH    16
#define DH    128
#define NBH   32          // B * NH
#define MROWS 4096        // B * T

typedef __bf16 bf16x8 __attribute__((ext_vector_type(8)));
typedef __bf16 bf16x4 __attribute__((ext_vector_type(4)));
typedef float  f32x4  __attribute__((ext_vector_type(4)));

#define MFMA16 __builtin_amdgcn_mfma_f32_16x16x32_bf16

__device__ __forceinline__ void async_copy16(const void* g, void* l) {
  __builtin_amdgcn_global_load_lds((const __attribute__((address_space(1))) void*)g,
                                   (__attribute__((address_space(3))) void*)l, 16, 0, 0);
}

// ---------------- prep kernels ----------------

__global__ void cast_bf16_k(const float* __restrict__ x, __bf16* __restrict__ xb) {
  int i = (blockIdx.x * 256 + threadIdx.x) * 4;
  float4 v = *reinterpret_cast<const float4*>(x + i);
  bf16x4 o;
  o[0] = (__bf16)v.x; o[1] = (__bf16)v.y; o[2] = (__bf16)v.z; o[3] = (__bf16)v.w;
  *reinterpret_cast<bf16x4*>(xb + i) = o;
}

// W [K][N] f32 -> WT [N][K] bf16
__global__ void transpose_cast_w(const float* __restrict__ W, __bf16* __restrict__ WT,
                                 int K, int N) {
  __shared__ float tile[32][33];
  int n0 = blockIdx.x * 32, k0 = blockIdx.y * 32;
  int tx = threadIdx.x, ty = threadIdx.y;
  #pragma unroll
  for (int i = 0; i < 4; i++)
    tile[ty + i * 8][tx] = W[(size_t)(k0 + ty + i * 8) * N + n0 + tx];
  __syncthreads();
  #pragma unroll
  for (int i = 0; i < 4; i++)
    WT[(size_t)(n0 + ty + i * 8) * K + k0 + tx] = (__bf16)tile[tx][ty + i * 8];
}

// Vb [BH][T][D] bf16 -> Vtb [BH][D][T] bf16
__global__ void transpose_v(const __bf16* __restrict__ Vb, __bf16* __restrict__ Vtb) {
  __shared__ __bf16 tile[32][34];
  int t0 = blockIdx.x * 32, d0 = blockIdx.y * 32, bh = blockIdx.z;
  const __bf16* src = Vb + (size_t)bh * T_SEQ * DH;
  __bf16* dst = Vtb + (size_t)bh * DH * T_SEQ;
  int tx = threadIdx.x, ty = threadIdx.y;
  #pragma unroll
  for (int i = 0; i < 4; i++)
    tile[ty + i * 8][tx] = src[(size_t)(t0 + ty + i * 8) * DH + d0 + tx];
  __syncthreads();
  #pragma unroll
  for (int i = 0; i < 4; i++)
    dst[(size_t)(d0 + ty + i * 8) * T_SEQ + t0 + tx] = tile[tx][ty + i * 8];
}

// ------- GEMM (C = A * Bt^T), BM=BN=128, BK=64, 4 waves, 1 barrier/K-tile -------
// LDS tile [128 rows][64 bf16] = 128-B rows, chunk-XOR swizzled (R4-verified).
// Epilogue: chunked LDS transpose -> per-thread 16 consecutive cols of one row
// -> register-adjacent RoPE pairs, coalesced float4 loads/stores (no RFO).

__device__ __forceinline__ bf16x8 rds(const __bf16* base, int row, int chunk) {
  return *reinterpret_cast<const bf16x8*>(
      reinterpret_cast<const char*>(base) + row * 128 + ((chunk ^ (row & 7)) << 4));
}

// stage one 128x64 tile (16 KB): 4 global_load_lds per wave (256-thread blocks)
__device__ __forceinline__ void stage64(const __bf16* g, int K, int kt, char* lds,
                                        int wave, int lane) {
  #pragma unroll
  for (int j = 0; j < 4; j++) {
    int r = wave * 32 + j * 8 + (lane >> 3);
    int c = lane & 7;
    const char* src = (const char*)g + (size_t)r * (K * 2) + kt * 128 + ((c ^ (r & 7)) << 4);
    async_copy16(src, lds + wave * 4096 + j * 1024);
  }
}

template <int EPI>
__global__ __launch_bounds__(256, 2) void gemm_bt(
    const __bf16* __restrict__ A, const __bf16* __restrict__ Bt, int K,
    const float* __restrict__ bias,
    const float* __restrict__ fcos, const float* __restrict__ fsin,
    __bf16* __restrict__ Qb, __bf16* __restrict__ Kb, __bf16* __restrict__ Vb,
    float* __restrict__ kout, float* __restrict__ vout,
    float* __restrict__ outp) {
  __shared__ __align__(16) char smem[65536];   // K-loop: A0,A1,B0,B1; epilogue: f32 scratch
  const int tid = threadIdx.x, lane = tid & 63, wave = tid >> 6;
  const int hi = lane >> 4, lo = lane & 15;
  const int wm = (wave >> 1) * 64, wn = (wave & 1) * 64;
  const __bf16* Ab = A + (size_t)blockIdx.y * 128 * K;
  const __bf16* Bb = Bt + (size_t)blockIdx.x * 128 * K;
  f32x4 acc[4][4] = {};
  const int NK = K >> 6;

  stage64(Ab, K, 0, smem, wave, lane);
  stage64(Bb, K, 0, smem + 32768, wave, lane);
  __syncthreads();   // drains vmcnt: tile 0 ready

  for (int t = 0; t < NK; ++t) {
    const int sel = (t & 1) ? 16384 : 0;
    const __bf16* Ac = (const __bf16*)(smem + sel);
    const __bf16* Bc = (const __bf16*)(smem + 32768 + sel);
    if (t + 1 < NK) {
      stage64(Ab, K, t + 1, smem + (sel ^ 16384), wave, lane);
      stage64(Bb, K, t + 1, smem + 32768 + (sel ^ 16384), wave, lane);
    }
    bf16x8 a0[4], b0[4], a1[4], b1[4];
    #pragma unroll
    for (int m = 0; m < 4; ++m) a0[m] = rds(Ac, wm + m * 16 + lo, hi);
    #pragma unroll
    for (int n = 0; n < 4; ++n) b0[n] = rds(Bc, wn + n * 16 + lo, hi);
    __builtin_amdgcn_s_setprio(1);
    #pragma unroll
    for (int m = 0; m < 4; ++m)
      #pragma unroll
      for (int n = 0; n < 4; ++n)
        acc[m][n] = MFMA16(a0[m], b0[n], acc[m][n], 0, 0, 0);
    __builtin_amdgcn_s_setprio(0);
    #pragma unroll
    for (int m = 0; m < 4; ++m) a1[m] = rds(Ac, wm + m * 16 + lo, 4 + hi);
    #pragma unroll
    for (int n = 0; n < 4; ++n) b1[n] = rds(Bc, wn + n * 16 + lo, 4 + hi);
    __builtin_amdgcn_s_setprio(1);
    #pragma unroll
    for (int m = 0; m < 4; ++m)
      #pragma unroll
      for (int n = 0; n < 4; ++n)
        acc[m][n] = MFMA16(a1[m], b1[n], acc[m][n], 0, 0, 0);
    __builtin_amdgcn_s_setprio(0);
    __syncthreads();   // all reads of cur done; staging drains via implicit vmcnt(0)
  }

  // ---- chunked LDS-transpose epilogue ----
  float* sc = (float*)smem;            // [32][132] f32 = 16.9 KB (aliases K-loop LDS)
  const int rl_r = tid >> 3;           // read row 0..31
  const int cb   = (tid & 7) * 16;     // read col block (16 consecutive)
  #pragma unroll
  for (int cc = 0; cc < 4; ++cc) {
    __syncthreads();                   // LDS free / prev chunk consumed
    if ((wave >> 1) == (cc >> 1)) {    // waves owning this 32-row chunk write it
      #pragma unroll
      for (int mm = 0; mm < 2; ++mm) {
        int m = (cc & 1) * 2 + mm;
        #pragma unroll
        for (int j = 0; j < 4; ++j) {
          int col = wn + j * 16 + lo;
          int rl = mm * 16 + hi * 4;
          #pragma unroll
          for (int r = 0; r < 4; ++r)
            sc[(rl + r) * 132 + col] = acc[m][j][r];
        }
      }
    }
    __syncthreads();
    float v[16];
    #pragma unroll
    for (int q = 0; q < 4; ++q)
      *reinterpret_cast<float4*>(&v[q * 4]) =
          *reinterpret_cast<const float4*>(&sc[rl_r * 132 + cb + q * 4]);
    const int row = blockIdx.y * 128 + cc * 32 + rl_r;
    const int n0  = blockIdx.x * 128 + cb;
    #pragma unroll
    for (int q = 0; q < 4; ++q) {
      float4 bv = *reinterpret_cast<const float4*>(&bias[n0 + q * 4]);
      v[q * 4 + 0] += bv.x; v[q * 4 + 1] += bv.y;
      v[q * 4 + 2] += bv.z; v[q * 4 + 3] += bv.w;
    }
    if (EPI == 1) {
      const int which = n0 >> 11;              // block-uniform (tile inside one of Q/K/V)
      const int wn2 = n0 & 2047, h = wn2 >> 7, d0 = wn2 & 127;
      const int b = row >> 11, tt = row & 2047;
      if (which < 2) {                         // RoPE: pairs are register-adjacent
        const float* cp = fcos + tt * 64 + (d0 >> 1);
        const float* sp = fsin + tt * 64 + (d0 >> 1);
        float4 c0 = *reinterpret_cast<const float4*>(cp);
        float4 c1 = *reinterpret_cast<const float4*>(cp + 4);
        float4 s0 = *reinterpret_cast<const float4*>(sp);
        float4 s1 = *reinterpret_cast<const float4*>(sp + 4);
        float cs[8] = {c0.x, c0.y, c0.z, c0.w, c1.x, c1.y, c1.z, c1.w};
        float sn[8] = {s0.x, s0.y, s0.z, s0.w, s1.x, s1.y, s1.z, s1.w};
        #pragma unroll
        for (int p = 0; p < 8; ++p) {
          float re = v[2 * p], im = v[2 * p + 1];
          v[2 * p]     = re * cs[p] - im * sn[p];
          v[2 * p + 1] = re * sn[p] + im * cs[p];
        }
      }
      size_t base = (((size_t)(b * NH + h)) * T_SEQ + tt) * DH + d0;
      bf16x8 o0, o1;
      #pragma unroll
      for (int p = 0; p < 8; ++p) { o0[p] = (__bf16)v[p]; o1[p] = (__bf16)v[8 + p]; }
      if (which == 0) {
        *reinterpret_cast<bf16x8*>(Qb + base) = o0;
        *reinterpret_cast<bf16x8*>(Qb + base + 8) = o1;
      } else if (which == 1) {
        *reinterpret_cast<bf16x8*>(Kb + base) = o0;
        *reinterpret_cast<bf16x8*>(Kb + base + 8) = o1;
        #pragma unroll
        for (int q = 0; q < 4; ++q)
          *reinterpret_cast<float4*>(kout + base + q * 4) =
              *reinterpret_cast<const float4*>(&v[q * 4]);
      } else {
        *reinterpret_cast<bf16x8*>(Vb + base) = o0;
        *reinterpret_cast<bf16x8*>(Vb + base + 8) = o1;
        #pragma unroll
        for (int q = 0; q < 4; ++q)
          *reinterpret_cast<float4*>(vout + base + q * 4) =
              *reinterpret_cast<const float4*>(&v[q * 4]);
      }
    } else {
      float* op = outp + (size_t)row * DM + n0;
      #pragma unroll
      for (int q = 0; q < 4; ++q)
        *reinterpret_cast<float4*>(op + q * 4) =
            *reinterpret_cast<const float4*>(&v[q * 4]);
    }
  }
}

// ---------------- flash attention (256 threads, 4 waves x 16 q-rows, QBLK=64) ----------------
// R7-proven sync: per tile {sync; stage; sync(drain); compute}. Q in REGISTERS
// (no Qs LDS). Ks [64][128]: 256-B rows; Vts [128 d][64 s] / P [16][64]: 128-B
// rows; all chunk-XOR swizzled. LDS 40 KB -> >=2 independent blocks/CU (separate
// barrier domains overlap each other's serial chains). Grid 512 = (bh, pair);
// pair j handles q-tiles j (pass 0) and 31-j (pass 1): exactly 33 kv-tile units
// per block. XCD remap keeps each head's K/V on one XCD's L2.

__device__ __forceinline__ bf16x8 lds_frag(const __bf16* base, int row, int chunk) {
  return *reinterpret_cast<const bf16x8*>(
      reinterpret_cast<const char*>(base) + row * 256 + ((chunk ^ (row & 7)) << 4));
}

// stage 64 rows x 256 B (16 KB) with 4 waves
__device__ __forceinline__ void stage64x256(const __bf16* g, __bf16* lds, int tid) {
  const int wave = tid >> 6, lane = tid & 63;
  #pragma unroll
  for (int j = 0; j < 4; j++) {
    int off = j * 4096 + wave * 1024;
    int r = (off >> 8) + (lane >> 4);
    int c = lane & 15;
    const char* gs = (const char*)g + (size_t)r * 256 + ((c ^ (r & 7)) << 4);
    async_copy16(gs, (char*)lds + off);
  }
}

// stage 128 rows x 128 B (16 KB) with 4 waves; source row stride rstrideB, col offset colB
__device__ __forceinline__ void stage128x128(const __bf16* g, size_t rstrideB, int colB,
                                             __bf16* lds, int tid) {
  const int wave = tid >> 6, lane = tid & 63;
  #pragma unroll
  for (int j = 0; j < 4; j++) {
    int off = j * 4096 + wave * 1024;
    int r = (off >> 7) + (lane >> 3);
    int c = lane & 7;
    const char* gs = (const char*)g + (size_t)r * rstrideB + colB + ((c ^ (r & 7)) << 4);
    async_copy16(gs, (char*)lds + off);
  }
}

__global__ __launch_bounds__(256, 2) void attn_fwd(
    const __bf16* __restrict__ Qb, const __bf16* __restrict__ Kb,
    const __bf16* __restrict__ Vtb, __bf16* __restrict__ att_out) {
  __shared__ __bf16 Ks[64 * 128];    // 16 KB
  __shared__ __bf16 Vts[128 * 64];   // 16 KB
  __shared__ __bf16 Ps[4 * 16 * 64]; // 8 KB (per-wave [16 q][64 s])  -> 40 KB
  const int tid = threadIdx.x, lane = tid & 63, wave = tid >> 6;
  const int hi = lane >> 4, lo = lane & 15;
  // XCD remap: 512 blocks; xcd = linear&7; per XCD: 4 heads x 16 pair-slots
  const int linear = (int)blockIdx.x;
  const int xcd = linear & 7, rest = linear >> 3;
  const int bh = xcd + 8 * (rest >> 4);
  const int pair = rest & 15;
  const int b = bh >> 4, h = bh & 15;
  const __bf16* Qg = Qb + (size_t)bh * T_SEQ * DH;
  const __bf16* Kg = Kb + (size_t)bh * T_SEQ * DH;
  const __bf16* Vg = Vtb + (size_t)bh * DH * T_SEQ;
  const float scale = 0.08838834764831845f;   // 1/sqrt(128)
  const float L2E = 1.4426950408889634f;
  __bf16* Pw = Ps + wave * 1024;

  for (int pass = 0; pass < 2; ++pass) {
    const int qj = pass ? (31 - pair) : pair;   // q-tile index (64 rows)
    const int q0 = qj * 64;
    const int qg = q0 + wave * 16 + lo;         // this lane's q row
    // Q fragments in registers (same bytes the LDS path would deliver)
    bf16x8 qf[4];
    const __bf16* qp = Qg + (size_t)qg * DH + hi * 8;
    #pragma unroll
    for (int ks = 0; ks < 4; ++ks) qf[ks] = *reinterpret_cast<const bf16x8*>(qp + ks * 32);
    f32x4 oacc[8] = {};
    float m = -3e38f, l = 0.f;
    const int NT = qj + 1;

    for (int kt = 0; kt < NT; ++kt) {
      __syncthreads();                        // prev tile reads done
      stage64x256(Kg + (size_t)kt * 64 * DH, Ks, tid);
      stage128x128(Vg, (size_t)T_SEQ * 2, kt * 128, Vts, tid);
      __syncthreads();                        // drains vmcnt(0): K/V ready

      // S^T = K · Q^T : A = K[s][d], B = Q^T[d][q]; C: row=s (hi*4+r), col=q (lo)
      f32x4 sacc[4] = {};
      __builtin_amdgcn_s_setprio(1);
      #pragma unroll
      for (int ks = 0; ks < 4; ++ks)
        #pragma unroll
        for (int sf = 0; sf < 4; ++sf) {
          bf16x8 ak = lds_frag(Ks, sf * 16 + lo, ks * 4 + hi);
          sacc[sf] = MFMA16(ak, qf[ks], sacc[sf], 0, 0, 0);
        }
      __builtin_amdgcn_s_setprio(0);
      const bool diag = (kt == NT - 1);
      float mx = -3e38f;
      #pragma unroll
      for (int sf = 0; sf < 4; ++sf)
        #pragma unroll
        for (int r = 0; r < 4; ++r) {
          float v = sacc[sf][r] * scale;
          if (diag && (kt * 64 + sf * 16 + hi * 4 + r) > qg) v = -3e38f;
          sacc[sf][r] = v;
          mx = fmaxf(mx, v);
        }
      mx = fmaxf(mx, __shfl_xor(mx, 16, 64));
      mx = fmaxf(mx, __shfl_xor(mx, 32, 64));
      // defer-max (T13): skip O-rescale when tile max doesn't exceed m by >8
      const bool nr = __all(mx - m <= 8.0f);
      if (!nr) {
        float mnew = fmaxf(m, mx);
        float alpha = __builtin_exp2f((m - mnew) * L2E);
        m = mnew;
        l *= alpha;
        #pragma unroll
        for (int df = 0; df < 8; ++df) {
          oacc[df][0] *= alpha; oacc[df][1] *= alpha;
          oacc[df][2] *= alpha; oacc[df][3] *= alpha;
        }
      }
      float rs = 0.f;
      #pragma unroll
      for (int sf = 0; sf < 4; ++sf)
        #pragma unroll
        for (int r = 0; r < 4; ++r) {
          float p = __builtin_exp2f((sacc[sf][r] - m) * L2E);
          sacc[sf][r] = p;
          rs += p;
        }
      rs += __shfl_xor(rs, 16, 64);
      rs += __shfl_xor(rs, 32, 64);
      l += rs;
      // write P tile: lane's 4 vals are contiguous s at row lo -> one b64
      #pragma unroll
      for (int sf = 0; sf < 4; ++sf) {
        bf16x4 pk;
        pk[0] = (__bf16)sacc[sf][0]; pk[1] = (__bf16)sacc[sf][1];
        pk[2] = (__bf16)sacc[sf][2]; pk[3] = (__bf16)sacc[sf][3];
        int byte = sf * 32 + hi * 8;
        int chunk = byte >> 4, rem = byte & 15;
        char* p = (char*)Pw + lo * 128 + (((chunk ^ (lo & 7)) << 4) | rem);
        *reinterpret_cast<bf16x4*>(p) = pk;
      }
      // PV: O^T += V^T · P^T : A = V^T[d][s] (Vts rows), B = P[q][s] rows
      __builtin_amdgcn_s_setprio(1);
      #pragma unroll
      for (int ks = 0; ks < 2; ++ks) {
        bf16x8 bp = rds(Pw, lo, ks * 4 + hi);
        #pragma unroll
        for (int df = 0; df < 8; ++df) {
          bf16x8 av = rds(Vts, df * 16 + lo, ks * 4 + hi);
          oacc[df] = MFMA16(av, bp, oacc[df], 0, 0, 0);
        }
      }
      __builtin_amdgcn_s_setprio(0);
    } // kt

    // epilogue: O^T lane holds d = df*16 + hi*4 + r, q = lo (wave's 16 rows)
    float inv = 1.0f / l;
    int qrow = b * T_SEQ + q0 + wave * 16 + lo;
    #pragma unroll
    for (int df = 0; df < 8; ++df) {
      bf16x4 pk;
      pk[0] = (__bf16)(oacc[df][0] * inv);
      pk[1] = (__bf16)(oacc[df][1] * inv);
      pk[2] = (__bf16)(oacc[df][2] * inv);
      pk[3] = (__bf16)(oacc[df][3] * inv);
      int d = df * 16 + hi * 4;
      *reinterpret_cast<bf16x4*>(att_out + (size_t)qrow * DM + h * DH + d) = pk;
    }
  } // pass
}

// ---------------- launch ----------------

extern "C" void kernel_launch(void* const* d_in, const int* in_sizes, int n_in,
                              void* d_out, int out_size, void* d_ws, size_t ws_size,
                              hipStream_t stream) {
  const float* x     = (const float*)d_in[0];
  // d_in[1] = causal mask: ignored (mask applied analytically)
  const float* fcos  = (const float*)d_in[2];
  const float* fsin  = (const float*)d_in[3];
  const float* Wqkv  = (const float*)d_in[4];
  const float* bqkv  = (const float*)d_in[5];
  const float* Wproj = (const float*)d_in[6];
  const float* bproj = (const float*)d_in[7];
  float* out  = (float*)d_out;
  float* kout = out + (size_t)8388608;
  float* vout = out + (size_t)16777216;

  char* ws = (char*)d_ws;
  __bf16* xb     = (__bf16*)(ws);                 // 16 MiB; reused as att_out later
  __bf16* WqkvT  = (__bf16*)(ws + 16777216);      // 24 MiB
  __bf16* WprojT = (__bf16*)(ws + 41943040);      // 8 MiB
  __bf16* Qb     = (__bf16*)(ws + 50331648);      // 16 MiB
  __bf16* Kb     = (__bf16*)(ws + 67108864);      // 16 MiB
  __bf16* Vb     = (__bf16*)(ws + 83886080);      // 16 MiB
  __bf16* Vtb    = (__bf16*)(ws + 100663296);     // 16 MiB  (total 112 MiB)
  __bf16* att    = xb;                            // alias: xb dead after gemm1

  cast_bf16_k<<<8192, 256, 0, stream>>>(x, xb);
  transpose_cast_w<<<dim3(192, 64), dim3(32, 8), 0, stream>>>(Wqkv, WqkvT, DM, 3 * DM);
  transpose_cast_w<<<dim3(64, 64), dim3(32, 8), 0, stream>>>(Wproj, WprojT, DM, DM);
  // QKV: M=4096 (by 0..31), N=6144 (bx 0..47) -> 1536 blocks
  gemm_bt<1><<<dim3(48, 32), 256, 0, stream>>>(xb, WqkvT, DM, bqkv, fcos, fsin,
                                               Qb, Kb, Vb, kout, vout, nullptr);
  transpose_v<<<dim3(64, 4, NBH), dim3(32, 8), 0, stream>>>(Vb, Vtb);
  // attn: 512 blocks = 32 bh x 16 pair-slots (XCD-remapped), 2 blocks/CU
  attn_fwd<<<512, 256, 0, stream>>>(Qb, Kb, Vtb, att);
  // proj: M=4096, N=2048 -> 16x32 = 512 blocks
  gemm_bt<0><<<dim3(16, 32), 256, 0, stream>>>(att, WprojT, DM, bproj, nullptr, nullptr,
                                               nullptr, nullptr, nullptr, nullptr, nullptr, out);
}

// Round 10
// 276.881 us; speedup vs baseline: 1.3371x; 1.0172x over previous
//
#include <hip/hip_runtime.h>
#include <hip/hip_bf16.h>

#define T_SEQ 2048
#define DM    2048
#define NH    16
#define DH    128
#define NBH   32          // B * NH
#define MROWS 4096        // B * T

typedef __bf16 bf16x8 __attribute__((ext_vector_type(8)));
typedef __bf16 bf16x4 __attribute__((ext_vector_type(4)));
typedef float  f32x4  __attribute__((ext_vector_type(4)));

#define MFMA16 __builtin_amdgcn_mfma_f32_16x16x32_bf16

__device__ __forceinline__ void async_copy16(const void* g, void* l) {
  __builtin_amdgcn_global_load_lds((const __attribute__((address_space(1))) void*)g,
                                   (__attribute__((address_space(3))) void*)l, 16, 0, 0);
}

// ---------------- prep kernels ----------------

__global__ void cast_bf16_k(const float* __restrict__ x, __bf16* __restrict__ xb) {
  int i = (blockIdx.x * 256 + threadIdx.x) * 4;
  float4 v = *reinterpret_cast<const float4*>(x + i);
  bf16x4 o;
  o[0] = (__bf16)v.x; o[1] = (__bf16)v.y; o[2] = (__bf16)v.z; o[3] = (__bf16)v.w;
  *reinterpret_cast<bf16x4*>(xb + i) = o;
}

// W [K][N] f32 -> WT [N][K] bf16
__global__ void transpose_cast_w(const float* __restrict__ W, __bf16* __restrict__ WT,
                                 int K, int N) {
  __shared__ float tile[32][33];
  int n0 = blockIdx.x * 32, k0 = blockIdx.y * 32;
  int tx = threadIdx.x, ty = threadIdx.y;
  #pragma unroll
  for (int i = 0; i < 4; i++)
    tile[ty + i * 8][tx] = W[(size_t)(k0 + ty + i * 8) * N + n0 + tx];
  __syncthreads();
  #pragma unroll
  for (int i = 0; i < 4; i++)
    WT[(size_t)(n0 + ty + i * 8) * K + k0 + tx] = (__bf16)tile[tx][ty + i * 8];
}

// Vb [BH][T][D] bf16 -> Vtb [BH][D][T] bf16
__global__ void transpose_v(const __bf16* __restrict__ Vb, __bf16* __restrict__ Vtb) {
  __shared__ __bf16 tile[32][34];
  int t0 = blockIdx.x * 32, d0 = blockIdx.y * 32, bh = blockIdx.z;
  const __bf16* src = Vb + (size_t)bh * T_SEQ * DH;
  __bf16* dst = Vtb + (size_t)bh * DH * T_SEQ;
  int tx = threadIdx.x, ty = threadIdx.y;
  #pragma unroll
  for (int i = 0; i < 4; i++)
    tile[ty + i * 8][tx] = src[(size_t)(t0 + ty + i * 8) * DH + d0 + tx];
  __syncthreads();
  #pragma unroll
  for (int i = 0; i < 4; i++)
    dst[(size_t)(d0 + ty + i * 8) * T_SEQ + t0 + tx] = tile[tx][ty + i * 8];
}

// ------- GEMM (C = A * Bt^T), BM=BN=128, BK=64, 4 waves, 1 barrier/K-tile -------
// LDS tile [128 rows][64 bf16] = 128-B rows, chunk-XOR swizzled (R4-verified).
// Epilogue: chunked LDS transpose -> per-thread 16 consecutive cols of one row
// -> register-adjacent RoPE pairs, coalesced float4 loads/stores (no RFO).

__device__ __forceinline__ bf16x8 rds(const __bf16* base, int row, int chunk) {
  return *reinterpret_cast<const bf16x8*>(
      reinterpret_cast<const char*>(base) + row * 128 + ((chunk ^ (row & 7)) << 4));
}

// stage one 128x64 tile (16 KB): 4 global_load_lds per wave (256-thread blocks)
__device__ __forceinline__ void stage64(const __bf16* g, int K, int kt, char* lds,
                                        int wave, int lane) {
  #pragma unroll
  for (int j = 0; j < 4; j++) {
    int r = wave * 32 + j * 8 + (lane >> 3);
    int c = lane & 7;
    const char* src = (const char*)g + (size_t)r * (K * 2) + kt * 128 + ((c ^ (r & 7)) << 4);
    async_copy16(src, lds + wave * 4096 + j * 1024);
  }
}

template <int EPI>
__global__ __launch_bounds__(256, 2) void gemm_bt(
    const __bf16* __restrict__ A, const __bf16* __restrict__ Bt, int K,
    const float* __restrict__ bias,
    const float* __restrict__ fcos, const float* __restrict__ fsin,
    __bf16* __restrict__ Qb, __bf16* __restrict__ Kb, __bf16* __restrict__ Vb,
    float* __restrict__ kout, float* __restrict__ vout,
    float* __restrict__ outp) {
  __shared__ __align__(16) char smem[65536];   // K-loop: A0,A1,B0,B1; epilogue: f32 scratch
  const int tid = threadIdx.x, lane = tid & 63, wave = tid >> 6;
  const int hi = lane >> 4, lo = lane & 15;
  const int wm = (wave >> 1) * 64, wn = (wave & 1) * 64;
  const __bf16* Ab = A + (size_t)blockIdx.y * 128 * K;
  const __bf16* Bb = Bt + (size_t)blockIdx.x * 128 * K;
  f32x4 acc[4][4] = {};
  const int NK = K >> 6;

  stage64(Ab, K, 0, smem, wave, lane);
  stage64(Bb, K, 0, smem + 32768, wave, lane);
  __syncthreads();   // drains vmcnt: tile 0 ready

  for (int t = 0; t < NK; ++t) {
    const int sel = (t & 1) ? 16384 : 0;
    const __bf16* Ac = (const __bf16*)(smem + sel);
    const __bf16* Bc = (const __bf16*)(smem + 32768 + sel);
    if (t + 1 < NK) {
      stage64(Ab, K, t + 1, smem + (sel ^ 16384), wave, lane);
      stage64(Bb, K, t + 1, smem + 32768 + (sel ^ 16384), wave, lane);
    }
    bf16x8 a0[4], b0[4], a1[4], b1[4];
    #pragma unroll
    for (int m = 0; m < 4; ++m) a0[m] = rds(Ac, wm + m * 16 + lo, hi);
    #pragma unroll
    for (int n = 0; n < 4; ++n) b0[n] = rds(Bc, wn + n * 16 + lo, hi);
    __builtin_amdgcn_s_setprio(1);
    #pragma unroll
    for (int m = 0; m < 4; ++m)
      #pragma unroll
      for (int n = 0; n < 4; ++n)
        acc[m][n] = MFMA16(a0[m], b0[n], acc[m][n], 0, 0, 0);
    __builtin_amdgcn_s_setprio(0);
    #pragma unroll
    for (int m = 0; m < 4; ++m) a1[m] = rds(Ac, wm + m * 16 + lo, 4 + hi);
    #pragma unroll
    for (int n = 0; n < 4; ++n) b1[n] = rds(Bc, wn + n * 16 + lo, 4 + hi);
    __builtin_amdgcn_s_setprio(1);
    #pragma unroll
    for (int m = 0; m < 4; ++m)
      #pragma unroll
      for (int n = 0; n < 4; ++n)
        acc[m][n] = MFMA16(a1[m], b1[n], acc[m][n], 0, 0, 0);
    __builtin_amdgcn_s_setprio(0);
    __syncthreads();   // all reads of cur done; staging drains via implicit vmcnt(0)
  }

  // ---- chunked LDS-transpose epilogue ----
  float* sc = (float*)smem;            // [32][132] f32 = 16.9 KB (aliases K-loop LDS)
  const int rl_r = tid >> 3;           // read row 0..31
  const int cb   = (tid & 7) * 16;     // read col block (16 consecutive)
  #pragma unroll
  for (int cc = 0; cc < 4; ++cc) {
    __syncthreads();                   // LDS free / prev chunk consumed
    if ((wave >> 1) == (cc >> 1)) {    // waves owning this 32-row chunk write it
      #pragma unroll
      for (int mm = 0; mm < 2; ++mm) {
        int m = (cc & 1) * 2 + mm;
        #pragma unroll
        for (int j = 0; j < 4; ++j) {
          int col = wn + j * 16 + lo;
          int rl = mm * 16 + hi * 4;
          #pragma unroll
          for (int r = 0; r < 4; ++r)
            sc[(rl + r) * 132 + col] = acc[m][j][r];
        }
      }
    }
    __syncthreads();
    float v[16];
    #pragma unroll
    for (int q = 0; q < 4; ++q)
      *reinterpret_cast<float4*>(&v[q * 4]) =
          *reinterpret_cast<const float4*>(&sc[rl_r * 132 + cb + q * 4]);
    const int row = blockIdx.y * 128 + cc * 32 + rl_r;
    const int n0  = blockIdx.x * 128 + cb;
    #pragma unroll
    for (int q = 0; q < 4; ++q) {
      float4 bv = *reinterpret_cast<const float4*>(&bias[n0 + q * 4]);
      v[q * 4 + 0] += bv.x; v[q * 4 + 1] += bv.y;
      v[q * 4 + 2] += bv.z; v[q * 4 + 3] += bv.w;
    }
    if (EPI == 1) {
      const int which = n0 >> 11;              // block-uniform (tile inside one of Q/K/V)
      const int wn2 = n0 & 2047, h = wn2 >> 7, d0 = wn2 & 127;
      const int b = row >> 11, tt = row & 2047;
      if (which < 2) {                         // RoPE: pairs are register-adjacent
        const float* cp = fcos + tt * 64 + (d0 >> 1);
        const float* sp = fsin + tt * 64 + (d0 >> 1);
        float4 c0 = *reinterpret_cast<const float4*>(cp);
        float4 c1 = *reinterpret_cast<const float4*>(cp + 4);
        float4 s0 = *reinterpret_cast<const float4*>(sp);
        float4 s1 = *reinterpret_cast<const float4*>(sp + 4);
        float cs[8] = {c0.x, c0.y, c0.z, c0.w, c1.x, c1.y, c1.z, c1.w};
        float sn[8] = {s0.x, s0.y, s0.z, s0.w, s1.x, s1.y, s1.z, s1.w};
        #pragma unroll
        for (int p = 0; p < 8; ++p) {
          float re = v[2 * p], im = v[2 * p + 1];
          v[2 * p]     = re * cs[p] - im * sn[p];
          v[2 * p + 1] = re * sn[p] + im * cs[p];
        }
      }
      size_t base = (((size_t)(b * NH + h)) * T_SEQ + tt) * DH + d0;
      bf16x8 o0, o1;
      #pragma unroll
      for (int p = 0; p < 8; ++p) { o0[p] = (__bf16)v[p]; o1[p] = (__bf16)v[8 + p]; }
      if (which == 0) {
        *reinterpret_cast<bf16x8*>(Qb + base) = o0;
        *reinterpret_cast<bf16x8*>(Qb + base + 8) = o1;
      } else if (which == 1) {
        *reinterpret_cast<bf16x8*>(Kb + base) = o0;
        *reinterpret_cast<bf16x8*>(Kb + base + 8) = o1;
        #pragma unroll
        for (int q = 0; q < 4; ++q)
          *reinterpret_cast<float4*>(kout + base + q * 4) =
              *reinterpret_cast<const float4*>(&v[q * 4]);
      } else {
        *reinterpret_cast<bf16x8*>(Vb + base) = o0;
        *reinterpret_cast<bf16x8*>(Vb + base + 8) = o1;
        #pragma unroll
        for (int q = 0; q < 4; ++q)
          *reinterpret_cast<float4*>(vout + base + q * 4) =
              *reinterpret_cast<const float4*>(&v[q * 4]);
      }
    } else {
      float* op = outp + (size_t)row * DM + n0;
      #pragma unroll
      for (int q = 0; q < 4; ++q)
        *reinterpret_cast<float4*>(op + q * 4) =
            *reinterpret_cast<const float4*>(&v[q * 4]);
    }
  }
}

// ---------------- flash attention (256 threads, 4 waves x 16 q-rows, QBLK=64) ----------------
// T14 reg-staged prefetch, provably ordered: global loads land in REGISTERS
// (no LDS hazard in flight); commit = ds_write consuming the regs (compiler
// inserts the vmcnt wait via register deps); __syncthreads (drains lgkm)
// separates commit from readers. Per tile:
//   sync; commit(regs->LDS); sync; issue reg-loads(kt+1); compute(kt)
// -> staging latency hides under the full compute phase. LDS single-buffered
// 40 KB. Q in registers. Grid 512 = (bh, pair) XCD-remapped; pair j does
// q-tiles j and 31-j -> exactly 33 kv-tile units per block.

__device__ __forceinline__ bf16x8 lds_frag(const __bf16* base, int row, int chunk) {
  return *reinterpret_cast<const bf16x8*>(
      reinterpret_cast<const char*>(base) + row * 256 + ((chunk ^ (row & 7)) << 4));
}

// issue K-tile (64 s x 128 d, 16 KB) reg-loads; layout matches linear LDS commit
__device__ __forceinline__ void ldK(const __bf16* Kg, int kt, int wave, int lane,
                                    bf16x8 k[4]) {
  const char* g = (const char*)(Kg + (size_t)kt * 64 * DH);
  #pragma unroll
  for (int j = 0; j < 4; j++) {
    int off = j * 4096 + wave * 1024;
    int r = (off >> 8) + (lane >> 4);
    int c = lane & 15;
    k[j] = *reinterpret_cast<const bf16x8*>(g + (size_t)r * 256 + ((c ^ (r & 7)) << 4));
  }
}

// issue V^T-tile (128 d x 64 s, 16 KB) reg-loads from Vtb (row stride T_SEQ*2 B)
__device__ __forceinline__ void ldV(const __bf16* Vg, int kt, int wave, int lane,
                                    bf16x8 v[4]) {
  const char* g = (const char*)Vg;
  const int colB = kt * 128;
  #pragma unroll
  for (int j = 0; j < 4; j++) {
    int off = j * 4096 + wave * 1024;
    int r = (off >> 7) + (lane >> 3);
    int c = lane & 7;
    v[j] = *reinterpret_cast<const bf16x8*>(g + (size_t)r * (T_SEQ * 2) + colB + ((c ^ (r & 7)) << 4));
  }
}

__device__ __forceinline__ void commitKV(__bf16* Ks, __bf16* Vts, int wave, int lane,
                                         const bf16x8 k[4], const bf16x8 v[4]) {
  #pragma unroll
  for (int j = 0; j < 4; j++)
    *reinterpret_cast<bf16x8*>((char*)Ks + j * 4096 + wave * 1024 + lane * 16) = k[j];
  #pragma unroll
  for (int j = 0; j < 4; j++)
    *reinterpret_cast<bf16x8*>((char*)Vts + j * 4096 + wave * 1024 + lane * 16) = v[j];
}

__global__ __launch_bounds__(256, 2) void attn_fwd(
    const __bf16* __restrict__ Qb, const __bf16* __restrict__ Kb,
    const __bf16* __restrict__ Vtb, __bf16* __restrict__ att_out) {
  __shared__ __bf16 Ks[64 * 128];    // 16 KB (single-buffered)
  __shared__ __bf16 Vts[128 * 64];   // 16 KB
  __shared__ __bf16 Ps[4 * 16 * 64]; // 8 KB (per-wave [16 q][64 s])  -> 40 KB
  const int tid = threadIdx.x, lane = tid & 63, wave = tid >> 6;
  const int hi = lane >> 4, lo = lane & 15;
  // XCD remap: 512 blocks; xcd = linear&7; per XCD: 4 heads x 16 pair-slots
  const int linear = (int)blockIdx.x;
  const int xcd = linear & 7, rest = linear >> 3;
  const int bh = xcd + 8 * (rest >> 4);
  const int pair = rest & 15;
  const int b = bh >> 4, h = bh & 15;
  const __bf16* Qg = Qb + (size_t)bh * T_SEQ * DH;
  const __bf16* Kg = Kb + (size_t)bh * T_SEQ * DH;
  const __bf16* Vg = Vtb + (size_t)bh * DH * T_SEQ;
  const float scale = 0.08838834764831845f;   // 1/sqrt(128)
  const float L2E = 1.4426950408889634f;
  __bf16* Pw = Ps + wave * 1024;

  for (int pass = 0; pass < 2; ++pass) {
    const int qj = pass ? (31 - pair) : pair;   // q-tile index (64 rows)
    const int q0 = qj * 64;
    const int qg = q0 + wave * 16 + lo;         // this lane's q row
    // Q fragments in registers
    bf16x8 qf[4];
    const __bf16* qp = Qg + (size_t)qg * DH + hi * 8;
    #pragma unroll
    for (int ks = 0; ks < 4; ++ks) qf[ks] = *reinterpret_cast<const bf16x8*>(qp + ks * 32);
    f32x4 oacc[8] = {};
    float m = -3e38f, l = 0.f;
    const int NT = qj + 1;

    bf16x8 kst[4], vst[4];
    ldK(Kg, 0, wave, lane, kst);
    ldV(Vg, 0, wave, lane, vst);

    for (int kt = 0; kt < NT; ++kt) {
      __syncthreads();                        // readers of tile kt-1 done (LDS free)
      commitKV(Ks, Vts, wave, lane, kst, vst);  // reg deps force the vmcnt wait
      __syncthreads();                        // tile kt visible to all (lgkm drained)
      if (kt + 1 < NT) {                      // issue next tile into regs (hides
        ldK(Kg, kt + 1, wave, lane, kst);     //  under the compute below)
        ldV(Vg, kt + 1, wave, lane, vst);
      }

      // S^T = K · Q^T : A = K[s][d], B = Q^T[d][q]; C: row=s (hi*4+r), col=q (lo)
      f32x4 sacc[4] = {};
      __builtin_amdgcn_s_setprio(1);
      #pragma unroll
      for (int ks = 0; ks < 4; ++ks)
        #pragma unroll
        for (int sf = 0; sf < 4; ++sf) {
          bf16x8 ak = lds_frag(Ks, sf * 16 + lo, ks * 4 + hi);
          sacc[sf] = MFMA16(ak, qf[ks], sacc[sf], 0, 0, 0);
        }
      __builtin_amdgcn_s_setprio(0);
      const bool diag = (kt == NT - 1);
      float mx = -3e38f;
      #pragma unroll
      for (int sf = 0; sf < 4; ++sf)
        #pragma unroll
        for (int r = 0; r < 4; ++r) {
          float v = sacc[sf][r] * scale;
          if (diag && (kt * 64 + sf * 16 + hi * 4 + r) > qg) v = -3e38f;
          sacc[sf][r] = v;
          mx = fmaxf(mx, v);
        }
      mx = fmaxf(mx, __shfl_xor(mx, 16, 64));
      mx = fmaxf(mx, __shfl_xor(mx, 32, 64));
      // defer-max (T13): skip O-rescale when tile max doesn't exceed m by >8
      const bool nr = __all(mx - m <= 8.0f);
      if (!nr) {
        float mnew = fmaxf(m, mx);
        float alpha = __builtin_exp2f((m - mnew) * L2E);
        m = mnew;
        l *= alpha;
        #pragma unroll
        for (int df = 0; df < 8; ++df) {
          oacc[df][0] *= alpha; oacc[df][1] *= alpha;
          oacc[df][2] *= alpha; oacc[df][3] *= alpha;
        }
      }
      float rs = 0.f;
      #pragma unroll
      for (int sf = 0; sf < 4; ++sf)
        #pragma unroll
        for (int r = 0; r < 4; ++r) {
          float p = __builtin_exp2f((sacc[sf][r] - m) * L2E);
          sacc[sf][r] = p;
          rs += p;
        }
      rs += __shfl_xor(rs, 16, 64);
      rs += __shfl_xor(rs, 32, 64);
      l += rs;
      // write P tile: lane's 4 vals are contiguous s at row lo -> one b64
      #pragma unroll
      for (int sf = 0; sf < 4; ++sf) {
        bf16x4 pk;
        pk[0] = (__bf16)sacc[sf][0]; pk[1] = (__bf16)sacc[sf][1];
        pk[2] = (__bf16)sacc[sf][2]; pk[3] = (__bf16)sacc[sf][3];
        int byte = sf * 32 + hi * 8;
        int chunk = byte >> 4, rem = byte & 15;
        char* p = (char*)Pw + lo * 128 + (((chunk ^ (lo & 7)) << 4) | rem);
        *reinterpret_cast<bf16x4*>(p) = pk;
      }
      // PV: O^T += V^T · P^T : A = V^T[d][s] (Vts rows), B = P[q][s] rows
      __builtin_amdgcn_s_setprio(1);
      #pragma unroll
      for (int ks = 0; ks < 2; ++ks) {
        bf16x8 bp = rds(Pw, lo, ks * 4 + hi);
        #pragma unroll
        for (int df = 0; df < 8; ++df) {
          bf16x8 av = rds(Vts, df * 16 + lo, ks * 4 + hi);
          oacc[df] = MFMA16(av, bp, oacc[df], 0, 0, 0);
        }
      }
      __builtin_amdgcn_s_setprio(0);
    } // kt

    // epilogue: O^T lane holds d = df*16 + hi*4 + r, q = lo (wave's 16 rows)
    float inv = 1.0f / l;
    int qrow = b * T_SEQ + q0 + wave * 16 + lo;
    #pragma unroll
    for (int df = 0; df < 8; ++df) {
      bf16x4 pk;
      pk[0] = (__bf16)(oacc[df][0] * inv);
      pk[1] = (__bf16)(oacc[df][1] * inv);
      pk[2] = (__bf16)(oacc[df][2] * inv);
      pk[3] = (__bf16)(oacc[df][3] * inv);
      int d = df * 16 + hi * 4;
      *reinterpret_cast<bf16x4*>(att_out + (size_t)qrow * DM + h * DH + d) = pk;
    }
  } // pass
}

// ---------------- launch ----------------

extern "C" void kernel_launch(void* const* d_in, const int* in_sizes, int n_in,
                              void* d_out, int out_size, void* d_ws, size_t ws_size,
                              hipStream_t stream) {
  const float* x     = (const float*)d_in[0];
  // d_in[1] = causal mask: ignored (mask applied analytically)
  const float* fcos  = (const float*)d_in[2];
  const float* fsin  = (const float*)d_in[3];
  const float* Wqkv  = (const float*)d_in[4];
  const float* bqkv  = (const float*)d_in[5];
  const float* Wproj = (const float*)d_in[6];
  const float* bproj = (const float*)d_in[7];
  float* out  = (float*)d_out;
  float* kout = out + (size_t)8388608;
  float* vout = out + (size_t)16777216;

  char* ws = (char*)d_ws;
  __bf16* xb     = (__bf16*)(ws);                 // 16 MiB; reused as att_out later
  __bf16* WqkvT  = (__bf16*)(ws + 16777216);      // 24 MiB
  __bf16* WprojT = (__bf16*)(ws + 41943040);      // 8 MiB
  __bf16* Qb     = (__bf16*)(ws + 50331648);      // 16 MiB
  __bf16* Kb     = (__bf16*)(ws + 67108864);      // 16 MiB
  __bf16* Vb     = (__bf16*)(ws + 83886080);      // 16 MiB
  __bf16* Vtb    = (__bf16*)(ws + 100663296);     // 16 MiB  (total 112 MiB)
  __bf16* att    = xb;                            // alias: xb dead after gemm1

  cast_bf16_k<<<8192, 256, 0, stream>>>(x, xb);
  transpose_cast_w<<<dim3(192, 64), dim3(32, 8), 0, stream>>>(Wqkv, WqkvT, DM, 3 * DM);
  transpose_cast_w<<<dim3(64, 64), dim3(32, 8), 0, stream>>>(Wproj, WprojT, DM, DM);
  // QKV: M=4096 (by 0..31), N=6144 (bx 0..47) -> 1536 blocks
  gemm_bt<1><<<dim3(48, 32), 256, 0, stream>>>(xb, WqkvT, DM, bqkv, fcos, fsin,
                                               Qb, Kb, Vb, kout, vout, nullptr);
  transpose_v<<<dim3(64, 4, NBH), dim3(32, 8), 0, stream>>>(Vb, Vtb);
  // attn: 512 blocks = 32 bh x 16 pair-slots (XCD-remapped), 2 blocks/CU
  attn_fwd<<<512, 256, 0, stream>>>(Qb, Kb, Vtb, att);
  // proj: M=4096, N=2048 -> 16x32 = 512 blocks
  gemm_bt<0><<<dim3(16, 32), 256, 0, stream>>>(att, WprojT, DM, bproj, nullptr, nullptr,
                                               nullptr, nullptr, nullptr, nullptr, nullptr, out);
}